// Round 8
// baseline (307.713 us; speedup 1.0000x reference)
//
#include <hip/hip_runtime.h>
#include <hip/hip_cooperative_groups.h>
#include <stdint.h>

namespace cg = cooperative_groups;

#define NB 4
#define KTOT 5480
#define PER_IMG 258720
#define SCORE_THR 0.02f
#define IOU_THR 0.45f
#define REL_BASE 0x3CA3D70Bu   // smallest float bits > 0.02f
#define JCH 10                 // rank j-chunks
#define JSZ 548                // KTOT / JCH
#define NMSCAP 512
#define ZN4 49216              // 787456 / 16
#define NBLK 256

__constant__ int cFEAT[6]    = {20,10,5,3,2,1};
__constant__ int cSTRIDE[6]  = {16,32,64,107,160,320};
__constant__ int cMIN[6]     = {48,100,150,202,253,304};
__constant__ int cMAX[6]     = {100,150,202,253,304,320};
__constant__ int cNFLAT[6]   = {192000,48000,12000,4320,1920,480};
__constant__ int cFLATOFF[6] = {0,192000,240000,252000,256320,258240};
__constant__ int cKSEL[6]    = {1000,1000,1000,1000,1000,480};
__constant__ int cKOFF[6]    = {0,1000,2000,3000,4000,5000};
__constant__ double cRATIO[6] = {1.0,1.0,0.5,2.0,1.0/3.0,3.0};
__constant__ int eTLEV[14]   = {0,0,0,0,0,0,0,0,1,1,2,3,4,5};
__constant__ int eTCHK[14]   = {0,1,2,3,4,5,6,7,0,1,0,0,0,0};
__constant__ int eNCH[6]     = {8,2,1,1,1,1};

__device__ __forceinline__ unsigned long long mk_key(unsigned kb, int lev, unsigned idx) {
  return ((unsigned long long)kb << 21) |
         (unsigned long long)(0x1FFFFFu ^ (((unsigned)lev << 18) | idx));
}

__device__ __forceinline__ unsigned long long shfl64(unsigned long long x, int src) {
  int lo = __shfl((int)(unsigned)(x & 0xffffffffull), src);
  int hi = __shfl((int)(unsigned)(x >> 32), src);
  return ((unsigned long long)(unsigned)hi << 32) | (unsigned)lo;
}

// ------------- LDS union: one 54.6KB block reused across phases ------------------
struct SmemSM { float tile[81 * 64]; };
struct SmemEM {
  unsigned long long wbuf[1024];
  unsigned long long ebuf[4096];
  unsigned sc[256];
  unsigned wcnt, ecnt, sbw, sbe, smode, sb1;
};
struct SmemFN {
  unsigned long long eqb[4096];
  unsigned sc[256];
  unsigned cntS, eqS, byteS, rS;
};
struct SmemRK { unsigned long long sk[JSZ]; };
struct SmemDC { double ba[6][6][4]; };
struct SmemNM {
  unsigned long long mask[NMSCAP][8];
  float ox1[NMSCAP], oy1[NMSCAP], ox2[NMSCAP], oy2[NMSCAP];
  float oar[NMSCAP], osc[NMSCAP];
  float rx1[NMSCAP], ry1[NMSCAP], rx2[NMSCAP], ry2[NMSCAP];
  unsigned short list[NMSCAP];
  unsigned ccnt[24], cbase[24];
  unsigned long long alive[8];
  int n;
};
union SmemU {
  SmemSM sm; SmemEM em; SmemFN fn; SmemRK rk; SmemDC dc; SmemNM nm;
};

__global__ void __launch_bounds__(256) k_mega(
    const float* c0, const float* c1, const float* c2,
    const float* c3, const float* c4, const float* c5,
    const float* g0, const float* g1, const float* g2,
    const float* g3, const float* g4, const float* g5,
    float* scores, unsigned long long* selkeys, float* boxes, float* oscore,
    unsigned char* lab8, unsigned* obmax_u, unsigned* ghist, unsigned* ctrl,
    unsigned long long* eqg, unsigned* rank_part, float* outp, float4* zbase)
{
  cg::grid_group gg = cg::this_grid();
  __shared__ SmemU smem;
  const int tid = threadIdx.x;
  const int blk = blockIdx.x;

  // ================= P0: zero obmax + ghist + ctrl =================
  {
    int i = blk * 256 + tid;
    if (i < ZN4) zbase[i] = make_float4(0.f, 0.f, 0.f, 0.f);
  }
  gg.sync();

  // ================= P1: tiled softmax + 13-bit histogram =================
  for (int t = blk; t < NB * 78; t += NBLK) {
    __syncthreads();
    int b = t / 78, rem = t % 78;
    int lev, a, cb;
    if (rem < 42)      { lev = 0; a = rem / 7;         cb = (rem % 7) * 64; }
    else if (rem < 54) { lev = 1; a = (rem - 42) >> 1; cb = ((rem - 42) & 1) * 64; }
    else               { lev = 2 + (rem - 54) / 6; a = (rem - 54) % 6; cb = 0; }
    const float* cls = (lev==0)?c0:(lev==1)?c1:(lev==2)?c2:(lev==3)?c3:(lev==4)?c4:c5;
    int f = cFEAT[lev], ff = f * f;
    int ncell = ff - cb; if (ncell > 64) ncell = 64;
    const float* base = cls + (size_t)(b * 486 + a * 81) * ff + cb;
    for (int t2 = tid; t2 < 81 * 64; t2 += 256) {
      int c = t2 >> 6, cell = t2 & 63;
      if (cell < ncell)
        smem.sm.tile[(c << 6) | (cell ^ (c & 63))] = base[c * ff + cell];
    }
    __syncthreads();
    int lane = tid & 63, w = tid >> 6;
    unsigned* h = ghist + (size_t)(b * 6 + lev) * 8192;
    for (int cell = w; cell < ncell; cell += 4) {
      float v1 = smem.sm.tile[(lane << 6) | (cell ^ lane)];
      float v2 = (lane <= 16) ? smem.sm.tile[((lane + 64) << 6) | (cell ^ lane)]
                              : __uint_as_float(0xff800000u);
      float mx = fmaxf(v1, v2);
      #pragma unroll
      for (int m = 32; m; m >>= 1) mx = fmaxf(mx, __shfl_xor(mx, m));
      float e1 = expf(v1 - mx);
      float e2 = (lane <= 16) ? expf(v2 - mx) : 0.f;
      float sm = e1 + e2;
      #pragma unroll
      for (int m = 32; m; m >>= 1) sm += __shfl_xor(sm, m);
      int row = (cb + cell) * 6 + a;
      float* outs = scores + (size_t)b * PER_IMG + cFLATOFF[lev] + row * 80;
      float p1 = e1 / sm;
      outs[lane] = (p1 > SCORE_THR) ? p1 : -1.f;
      if (p1 > SCORE_THR)
        atomicAdd(&h[(__float_as_uint(p1) - REL_BASE) >> 13], 1u);
      if (lane < 16) {
        float p2 = e2 / sm;
        outs[lane + 64] = (p2 > SCORE_THR) ? p2 : -1.f;
        if (p2 > SCORE_THR)
          atomicAdd(&h[(__float_as_uint(p2) - REL_BASE) >> 13], 1u);
      }
    }
  }
  gg.sync();

  // ================= P2: emit (with inline plan) =================
  if (blk < NB * 14) {
    int b = blk / 14, ent = blk % 14;
    int lev = eTLEV[ent], chk = eTCHK[ent];
    int task = b * 6 + lev;
    int n = cNFLAT[lev];
    const float* s = scores + (size_t)b * PER_IMG + cFLATOFF[lev];
    unsigned long long* outk = selkeys + (size_t)b * KTOT + cKOFF[lev];
    if (lev == 5) {
      for (int i = tid; i < n; i += 256) {
        float v = s[i];
        unsigned kb = (v > SCORE_THR) ? __float_as_uint(v) : 0u;
        outk[i] = mk_key(kb, lev, (unsigned)i);
      }
    } else {
      unsigned kk = (unsigned)cKSEL[lev];
      // --- inline plan: suffix-scan of 8192-bin histogram ---
      {
        const unsigned* h = ghist + (size_t)task * 8192;
        unsigned loc[32]; unsigned ssum = 0;
        #pragma unroll
        for (int j = 0; j < 32; ++j) { loc[j] = h[tid * 32 + j]; ssum += loc[j]; }
        smem.em.sc[tid] = ssum;
        __syncthreads();
        for (int off = 1; off < 256; off <<= 1) {
          unsigned cur = smem.em.sc[tid];
          unsigned add = (tid + off < 256) ? smem.em.sc[tid + off] : 0u;
          __syncthreads();
          smem.em.sc[tid] = cur + add;
          __syncthreads();
        }
        unsigned call = smem.em.sc[0];
        if (call < kk) { if (tid == 0) smem.em.smode = 1u; }
        else {
          unsigned above = (tid == 255) ? 0u : smem.em.sc[tid + 1];
          unsigned run = above;
          #pragma unroll
          for (int j = 31; j >= 0; --j) {
            unsigned hj = loc[j];
            if (run < kk && run + hj >= kk) {
              smem.em.smode = 0u; smem.em.sb1 = (unsigned)(tid * 32 + j);
            }
            run += hj;
          }
        }
        __syncthreads();
      }
      unsigned mode = smem.em.smode;
      unsigned b1 = (mode == 0u) ? smem.em.sb1 : 0u;
      if (tid == 0) { smem.em.wcnt = 0; smem.em.ecnt = 0; }
      __syncthreads();
      int csz = n / eNCH[lev];
      int start = chk * csz;
      const float4* s4 = (const float4*)(s + start);
      int n4 = csz >> 2;
      if (mode == 0u) {
        unsigned base_lo = REL_BASE + (b1 << 13);
        unsigned base_hi = base_lo + 8192u;
        #pragma unroll 4
        for (int i0 = tid; i0 < n4; i0 += 256) {
          float4 vv = s4[i0];
          #pragma unroll
          for (int e2 = 0; e2 < 4; ++e2) {
            float v = (e2==0)?vv.x:(e2==1)?vv.y:(e2==2)?vv.z:vv.w;
            if (v > SCORE_THR) {
              unsigned kb = __float_as_uint(v);
              unsigned idx = (unsigned)(start + i0 * 4 + e2);
              if (kb >= base_hi) {
                unsigned p = atomicAdd(&smem.em.wcnt, 1u);
                if (p < 1024u) smem.em.wbuf[p] = mk_key(kb, lev, idx);
              } else if (kb >= base_lo) {
                unsigned p = atomicAdd(&smem.em.ecnt, 1u);
                if (p < 4096u) smem.em.ebuf[p] = mk_key(kb, lev, idx);
              }
            }
          }
        }
      } else {
        #pragma unroll 4
        for (int i0 = tid; i0 < n4; i0 += 256) {
          float4 vv = s4[i0];
          #pragma unroll
          for (int e2 = 0; e2 < 4; ++e2) {
            float v = (e2==0)?vv.x:(e2==1)?vv.y:(e2==2)?vv.z:vv.w;
            if (v > SCORE_THR) {
              unsigned p = atomicAdd(&smem.em.wcnt, 1u);
              if (p < 1024u) smem.em.wbuf[p] = mk_key(__float_as_uint(v), lev,
                                                      (unsigned)(start + i0 * 4 + e2));
            }
          }
        }
      }
      __syncthreads();
      if (tid == 0) {
        smem.em.sbw = atomicAdd(&ctrl[task * 8 + 2], smem.em.wcnt);
        smem.em.sbe = atomicAdd(&ctrl[task * 8 + 3], smem.em.ecnt);
      }
      __syncthreads();
      unsigned nw = (smem.em.wcnt < 1024u) ? smem.em.wcnt : 1024u;
      unsigned ne = (smem.em.ecnt < 4096u) ? smem.em.ecnt : 4096u;
      unsigned bw = smem.em.sbw, be = smem.em.sbe;
      for (unsigned t = tid; t < nw; t += 256) outk[bw + t] = smem.em.wbuf[t];
      for (unsigned t = tid; t < ne; t += 256) {
        unsigned g = be + t;
        if (g < 4096u) eqg[(size_t)task * 4096 + g] = smem.em.ebuf[t];
      }
    }
  }
  gg.sync();

  // ================= P3: finalize (ties / fillers / pathological) =================
  if (blk < NB * 6) {
    int task = blk;
    int b = task / 6, lev = task % 6;
    if (lev != 5) {
      unsigned kk = (unsigned)cKSEL[lev];
      int n = cNFLAT[lev];
      const float* s = scores + (size_t)b * PER_IMG + cFLATOFF[lev];
      unsigned long long* outk = selkeys + (size_t)b * KTOT + cKOFF[lev];
      unsigned levtag = (unsigned)lev << 18;
      const unsigned* h = ghist + (size_t)task * 8192;
      // total candidate count -> mode
      unsigned ssum = 0;
      #pragma unroll
      for (int j = 0; j < 32; ++j) ssum += h[tid * 32 + j];
      smem.fn.sc[tid] = ssum;
      __syncthreads();
      for (int off = 128; off >= 1; off >>= 1) {
        if (tid < off) smem.fn.sc[tid] += smem.fn.sc[tid + off];
        __syncthreads();
      }
      unsigned call = smem.fn.sc[0];
      __syncthreads();
      unsigned mode = (call >= kk) ? 0u : 1u;
      bool done = false;

      if (mode == 0u) {
        unsigned cnt = ctrl[task * 8 + 2];
        unsigned e = ctrl[task * 8 + 3];
        unsigned need = kk - cnt;
        if (e <= 4096u) {
          const unsigned long long* eq = eqg + (size_t)task * 4096;
          if (e == need) {
            for (unsigned t = tid; t < need; t += 256) outk[cnt + t] = eq[t];
          } else {
            unsigned P = 1; while (P < e) P <<= 1;
            for (unsigned t = tid; t < P; t += 256)
              smem.fn.eqb[t] = (t < e) ? eq[t] : 0ull;
            __syncthreads();
            for (unsigned sz = 2; sz <= P; sz <<= 1)
              for (unsigned st = sz >> 1; st; st >>= 1) {
                for (unsigned w2 = tid; w2 < P / 2; w2 += 256) {
                  unsigned i = ((w2 & ~(st - 1)) << 1) | (w2 & (st - 1));
                  unsigned l = i | st;
                  bool up = ((i & sz) == 0);
                  unsigned long long A = smem.fn.eqb[i], B = smem.fn.eqb[l];
                  if ((A < B) == up) { smem.fn.eqb[i] = B; smem.fn.eqb[l] = A; }
                }
                __syncthreads();
              }
            for (unsigned t = tid; t < need; t += 256) outk[cnt + t] = smem.fn.eqb[t];
          }
          done = true;
        }
      } else {
        // mode 1: candidates already emitted; append ordered fillers
        unsigned c = ctrl[task * 8 + 2];
        unsigned need = kk - c;
        unsigned base = 0;
        for (int start = 0; start < n && base < need; start += 256) {
          int i = start + tid;
          unsigned pred = (i < n && !(s[i] > SCORE_THR)) ? 1u : 0u;
          smem.fn.sc[tid] = pred;
          __syncthreads();
          for (int off = 1; off < 256; off <<= 1) {
            unsigned add = (tid >= off) ? smem.fn.sc[tid - off] : 0u;
            unsigned v = smem.fn.sc[tid];
            __syncthreads();
            smem.fn.sc[tid] = v + add;
            __syncthreads();
          }
          unsigned incl = smem.fn.sc[tid];
          unsigned total = smem.fn.sc[255];
          unsigned excl = incl - pred;
          if (pred && (base + excl) < need)
            outk[c + base + excl] =
                (unsigned long long)(0x1FFFFFu ^ (levtag | (unsigned)i));
          __syncthreads();
          base += total;
        }
        done = true;
      }

      if (!done) {
        // pathological eq-overflow: exact byte-radix reselect
        unsigned* hist = smem.fn.sc;
        unsigned* equ = (unsigned*)smem.fn.eqb;
        unsigned prefix = 0, r = kk;
        for (int pass = 3; pass >= 0; --pass) {
          int shift = pass * 8;
          hist[tid] = 0;
          __syncthreads();
          for (int i = tid; i < n; i += 256) {
            float v = s[i];
            unsigned kb = (v > SCORE_THR) ? __float_as_uint(v) : 0u;
            bool match = (pass == 3) || (((kb ^ prefix) >> (shift + 8)) == 0u);
            if (match) atomicAdd(&hist[(kb >> shift) & 255u], 1u);
          }
          __syncthreads();
          if (tid == 0) {
            unsigned cum = 0, byte = 0, rr = r;
            for (int bb = 255; bb >= 0; --bb) {
              unsigned hh = hist[bb];
              if (cum + hh >= r) { byte = (unsigned)bb; rr = r - cum; break; }
              cum += hh;
            }
            smem.fn.byteS = byte; smem.fn.rS = rr;
          }
          __syncthreads();
          prefix |= (smem.fn.byteS << shift);
          r = smem.fn.rS;
          __syncthreads();
        }
        unsigned Kstar = prefix;
        if (tid == 0) { smem.fn.cntS = 0; smem.fn.eqS = 0; }
        __syncthreads();
        for (int i = tid; i < n; i += 256) {
          float v = s[i];
          unsigned kb = (v > SCORE_THR) ? __float_as_uint(v) : 0u;
          if (kb > Kstar) {
            unsigned slot = atomicAdd(&smem.fn.cntS, 1u);
            outk[slot] = mk_key(kb, lev, (unsigned)i);
          } else if (kb == Kstar) {
            unsigned es = atomicAdd(&smem.fn.eqS, 1u);
            if (es < 4096u) equ[es] = (unsigned)i;
          }
        }
        __syncthreads();
        unsigned m = smem.fn.cntS;
        unsigned e2 = (smem.fn.eqS < 4096u) ? smem.fn.eqS : 4096u;
        unsigned need2 = kk - m;
        if (e2 > need2) {
          unsigned P = 1; while (P < e2) P <<= 1;
          for (unsigned t = tid; t < P; t += 256) if (t >= e2) equ[t] = 0xFFFFFFFFu;
          __syncthreads();
          for (unsigned sz = 2; sz <= P; sz <<= 1)
            for (unsigned st = sz >> 1; st; st >>= 1) {
              for (unsigned w2 = tid; w2 < P / 2; w2 += 256) {
                unsigned i = ((w2 & ~(st - 1)) << 1) | (w2 & (st - 1));
                unsigned l = i | st;
                bool up = ((i & sz) == 0);
                unsigned A = equ[i], B = equ[l];
                if ((A > B) == up) { equ[i] = B; equ[l] = A; }
              }
              __syncthreads();
            }
        }
        __syncthreads();
        for (unsigned t = tid; t < need2; t += 256)
          outk[m + t] = ((unsigned long long)Kstar << 21) |
                        (unsigned long long)(0x1FFFFFu ^ (levtag | equ[t]));
      }
    }
  }
  gg.sync();

  // ================= P4: partitioned O(N^2) rank =================
  for (int t = blk; t < NB * 22 * JCH; t += NBLK) {
    int jc = t % JCH;
    int rest = t / JCH;
    int ic = rest % 22, b = rest / 22;
    __syncthreads();
    const unsigned long long* keys = selkeys + (size_t)b * KTOT;
    for (int j = tid; j < JSZ; j += 256) smem.rk.sk[j] = keys[jc * JSZ + j];
    int i = ic * 256 + tid;
    unsigned long long mk = (i < KTOT) ? keys[i] : 0ull;
    __syncthreads();
    unsigned r = 0;
    const ulonglong2* sk2 = (const ulonglong2*)smem.rk.sk;
    #pragma unroll 8
    for (int j = 0; j < JSZ / 2; ++j) {
      ulonglong2 kk2 = sk2[j];
      r += (kk2.x > mk) ? 1u : 0u;
      r += (kk2.y > mk) ? 1u : 0u;
    }
    if (i < KTOT) rank_part[((size_t)jc * NB + b) * KTOT + i] = r;
  }
  gg.sync();

  // ================= P5: sum partials + decode + scatter =================
  if (blk < NB * 22) {
    int b = blk / 22, ic = blk % 22;
    int i = ic * 256 + tid;
    if (tid < 36) {
      int lev = tid / 6, a = tid % 6;
      double base = (double)cMIN[lev];
      double scl = (a == 1) ? sqrt((double)cMAX[lev] / (double)cMIN[lev]) : 1.0;
      double hr = sqrt(cRATIO[a]);
      double wr = 1.0 / hr;
      double wsz = base * scl * wr;
      double hsz = base * scl * hr;
      double cc = (double)cSTRIDE[lev] / 2.0;
      smem.dc.ba[lev][a][0] = cc - 0.5 * wsz;
      smem.dc.ba[lev][a][1] = cc - 0.5 * hsz;
      smem.dc.ba[lev][a][2] = cc + 0.5 * wsz;
      smem.dc.ba[lev][a][3] = cc + 0.5 * hsz;
    }
    __syncthreads();
    float lmax = 0.f;
    if (i < KTOT) {
      unsigned long long mk = selkeys[(size_t)b * KTOT + i];
      unsigned r = 0;
      #pragma unroll
      for (int jc = 0; jc < JCH; ++jc)
        r += rank_part[((size_t)jc * NB + b) * KTOT + i];
      unsigned tag = 0x1FFFFFu ^ (unsigned)(mk & 0x1FFFFFull);
      int lev = tag >> 18;
      int fi = tag & 0x3FFFF;
      unsigned vb2 = (unsigned)(mk >> 21);
      int valid = (vb2 != 0u);
      float score = valid ? __uint_as_float(vb2) : 0.f;
      int label = fi % 80;
      int arow = fi / 80;
      int a = arow % 6, cell = arow / 6;
      int f = cFEAT[lev], ff = f * f;
      int x = cell % f, y = cell / f;
      const float* gb = (lev==0)?g0:(lev==1)?g1:(lev==2)?g2:(lev==3)?g3:(lev==4)?g4:g5;
      const float* pb = gb + (size_t)(b * 24 + a * 4) * ff + y * f + x;
      float d0 = pb[0] * 0.1f, d1 = pb[ff] * 0.1f;
      float d2 = pb[2 * ff] * 0.2f, d3 = pb[3 * ff] * 0.2f;
      const float MR = (float)4.135166556742356;
      d2 = fminf(fmaxf(d2, -MR), MR);
      d3 = fminf(fmaxf(d3, -MR), MR);
      double shx = (double)(x * cSTRIDE[lev]);
      double shy = (double)(y * cSTRIDE[lev]);
      float p0 = (float)(smem.dc.ba[lev][a][0] + shx);
      float p1 = (float)(smem.dc.ba[lev][a][1] + shy);
      float p2 = (float)(smem.dc.ba[lev][a][2] + shx);
      float p3 = (float)(smem.dc.ba[lev][a][3] + shy);
      float pxc = (p0 + p2) * 0.5f, pyc = (p1 + p3) * 0.5f;
      float pw = p2 - p0, ph = p3 - p1;
      float gx = pxc + pw * d0, gy = pyc + ph * d1;
      float gw = pw * expf(d2), gh = ph * expf(d3);
      float x1 = gx - 0.5f * gw, y1 = gy - 0.5f * gh;
      float x2 = gx + 0.5f * gw, y2 = gy + 0.5f * gh;
      x1 = fminf(fmaxf(x1, 0.f), 320.f);
      y1 = fminf(fmaxf(y1, 0.f), 320.f);
      x2 = fminf(fmaxf(x2, 0.f), 320.f);
      y2 = fminf(fmaxf(y2, 0.f), 320.f);
      size_t o = (size_t)b * KTOT + (size_t)r;
      boxes[o * 4 + 0] = x1; boxes[o * 4 + 1] = y1;
      boxes[o * 4 + 2] = x2; boxes[o * 4 + 3] = y2;
      oscore[o] = score;
      lab8[o] = valid ? (unsigned char)label : (unsigned char)0xFF;
      outp[(size_t)NB * KTOT * 5 + o] = (float)label;
      if (!valid) {
        float* det = outp + o * 5;
        det[0] = 0.f; det[1] = 0.f; det[2] = 0.f; det[3] = 0.f; det[4] = 0.f;
        outp[(size_t)NB * KTOT * 6 + o] = 0.f;
      }
      lmax = fmaxf(fmaxf(x1, y1), fmaxf(x2, y2));
    }
    #pragma unroll
    for (int m = 32; m; m >>= 1) lmax = fmaxf(lmax, __shfl_xor(lmax, m));
    if ((tid & 63) == 0) atomicMax(&obmax_u[b], __float_as_uint(lmax));
  }
  gg.sync();

  // ================= P6: mask-matrix NMS =================
  for (int t0 = blk; t0 < NB * 80; t0 += NBLK) {
    __syncthreads();
    int b = t0 / 80, cls2 = t0 % 80;
    int lane = tid & 63, w = tid >> 6;
    float ofs = (float)cls2 * (__uint_as_float(obmax_u[b]) + 1.0f);
    const unsigned* lb32 = (const unsigned*)(lab8 + (size_t)b * KTOT);

    // phase 1: ordered per-class list
    unsigned long long balA[6][4];
    #pragma unroll
    for (int ci = 0; ci < 6; ++ci) {
      int chunk = w + ci * 4;
      unsigned v = 0xFFFFFFFFu;
      if (chunk < 22) {
        int u = chunk * 64 + lane;
        if (u < KTOT / 4) v = lb32[u];
      }
      unsigned long long m0 = __ballot(((v      ) & 0xFFu) == (unsigned)cls2);
      unsigned long long m1 = __ballot(((v >>  8) & 0xFFu) == (unsigned)cls2);
      unsigned long long m2 = __ballot(((v >> 16) & 0xFFu) == (unsigned)cls2);
      unsigned long long m3 = __ballot(((v >> 24) & 0xFFu) == (unsigned)cls2);
      balA[ci][0] = m0; balA[ci][1] = m1; balA[ci][2] = m2; balA[ci][3] = m3;
      if (chunk < 22 && lane == 0)
        smem.nm.ccnt[chunk] =
            (unsigned)(__popcll(m0) + __popcll(m1) + __popcll(m2) + __popcll(m3));
    }
    __syncthreads();
    if (tid == 0) {
      unsigned tot = 0;
      for (int c = 0; c < 22; ++c) { smem.nm.cbase[c] = tot; tot += smem.nm.ccnt[c]; }
      smem.nm.n = (tot < NMSCAP) ? (int)tot : NMSCAP;
    }
    __syncthreads();
    int nn = smem.nm.n;
    unsigned long long blt = (lane == 0) ? 0ull : ((~0ull) >> (64 - lane));
    #pragma unroll
    for (int ci = 0; ci < 6; ++ci) {
      int chunk = w + ci * 4;
      if (chunk < 22) {
        unsigned pos = smem.nm.cbase[chunk];
        unsigned below = (unsigned)(__popcll(balA[ci][0] & blt) + __popcll(balA[ci][1] & blt) +
                                    __popcll(balA[ci][2] & blt) + __popcll(balA[ci][3] & blt));
        unsigned within = 0;
        #pragma unroll
        for (int k2 = 0; k2 < 4; ++k2) {
          if ((balA[ci][k2] >> lane) & 1ull) {
            unsigned mypos = pos + below + within;
            if (mypos < NMSCAP)
              smem.nm.list[mypos] = (unsigned short)(chunk * 256 + lane * 4 + k2);
            ++within;
          }
        }
      }
    }
    __syncthreads();

    // phase 2: load boxes
    for (int t = tid; t < nn; t += 256) {
      int pos = smem.nm.list[t];
      size_t o = (size_t)b * KTOT + pos;
      float4 bb = *(const float4*)(boxes + o * 4);
      smem.nm.rx1[t] = bb.x; smem.nm.ry1[t] = bb.y;
      smem.nm.rx2[t] = bb.z; smem.nm.ry2[t] = bb.w;
      float a1 = bb.x + ofs, b1 = bb.y + ofs, a2 = bb.z + ofs, b2 = bb.w + ofs;
      smem.nm.ox1[t] = a1; smem.nm.oy1[t] = b1;
      smem.nm.ox2[t] = a2; smem.nm.oy2[t] = b2;
      smem.nm.oar[t] = (a2 - a1) * (b2 - b1);
      smem.nm.osc[t] = oscore[o];
    }
    __syncthreads();

    // phase 3: suppression-mask matrix (upper triangle)
    int nw = (nn + 63) >> 6;
    for (int i = tid; i < nn; i += 256) {
      float ax1 = smem.nm.ox1[i], ay1 = smem.nm.oy1[i];
      float ax2 = smem.nm.ox2[i], ay2 = smem.nm.oy2[i], aar = smem.nm.oar[i];
      int w0 = i >> 6;
      for (int wd = w0; wd < nw; ++wd) {
        unsigned long long m = 0;
        int jbase = wd << 6;
        int jend = nn - jbase; if (jend > 64) jend = 64;
        for (int jj = 0; jj < jend; ++jj) {
          int j = jbase + jj;
          if (j > i) {
            float ix1 = fmaxf(ax1, smem.nm.ox1[j]);
            float iy1 = fmaxf(ay1, smem.nm.oy1[j]);
            float ix2 = fminf(ax2, smem.nm.ox2[j]);
            float iy2 = fminf(ay2, smem.nm.oy2[j]);
            float iw = fmaxf(ix2 - ix1, 0.f);
            float ih = fmaxf(iy2 - iy1, 0.f);
            float inter = iw * ih;
            float iou = inter / (aar + smem.nm.oar[j] - inter);
            if (iou > IOU_THR) m |= (1ull << jj);
          }
        }
        smem.nm.mask[i][wd] = m;
      }
    }
    __syncthreads();

    // phase 4: greedy walk on wave 0
    if (w == 0) {
      unsigned long long aw = 0;
      if (lane < nw) {
        int rem = nn - (lane << 6);
        aw = (rem >= 64) ? ~0ull : ((1ull << rem) - 1ull);
      }
      for (int i = 0; i < nn; ++i) {
        int wi = i >> 6;
        unsigned long long mrow = (lane >= wi && lane < nw) ? smem.nm.mask[i][lane] : 0ull;
        unsigned long long tw = shfl64(aw, wi);
        if ((tw >> (i & 63)) & 1ull) aw &= ~mrow;
      }
      if (lane < 8) smem.nm.alive[lane] = aw;
    }
    __syncthreads();

    // phase 5: write final det rows + keep column
    for (int t = tid; t < nn; t += 256) {
      float kf = ((smem.nm.alive[t >> 6] >> (t & 63)) & 1ull) ? 1.f : 0.f;
      int pos = smem.nm.list[t];
      size_t o = (size_t)b * KTOT + pos;
      float* det = outp + o * 5;
      det[0] = smem.nm.rx1[t] * kf; det[1] = smem.nm.ry1[t] * kf;
      det[2] = smem.nm.rx2[t] * kf; det[3] = smem.nm.ry2[t] * kf;
      det[4] = smem.nm.osc[t] * kf;
      outp[(size_t)NB * KTOT * 6 + o] = kf;
    }
  }
}

extern "C" void kernel_launch(void* const* d_in, const int* in_sizes, int n_in,
                              void* d_out, int out_size, void* d_ws, size_t ws_size,
                              hipStream_t stream) {
  (void)in_sizes; (void)n_in; (void)out_size; (void)ws_size;
  const float* c0 = (const float*)d_in[0];
  const float* g0 = (const float*)d_in[1];
  const float* c1 = (const float*)d_in[2];
  const float* g1 = (const float*)d_in[3];
  const float* c2 = (const float*)d_in[4];
  const float* g2 = (const float*)d_in[5];
  const float* c3 = (const float*)d_in[6];
  const float* g3 = (const float*)d_in[7];
  const float* c4 = (const float*)d_in[8];
  const float* g4 = (const float*)d_in[9];
  const float* c5 = (const float*)d_in[10];
  const float* g5 = (const float*)d_in[11];

  char* ws = (char*)d_ws;
  float* scores = (float*)ws;                                         // 4,139,520
  unsigned* rank_part = (unsigned*)ws;                                // aliases scores
  unsigned long long* selkeys = (unsigned long long*)(ws + 4139520);  // 175,360
  float* boxes  = (float*)(ws + 4314880);                             // 350,720
  float* oscore = (float*)(ws + 4665600);                             // 87,680
  unsigned char* lab8 = (unsigned char*)(ws + 4753280);               // 21,920
  unsigned* obmax_u = (unsigned*)(ws + 5016320);                      // 256
  unsigned* ghist = (unsigned*)(ws + 5016576);                        // 786,432
  unsigned* ctrl  = (unsigned*)(ws + 5803008);                        // 768
  unsigned long long* eqg = (unsigned long long*)(ws + 5803776);      // 786,432
  float* outp = (float*)d_out;
  float4* zbase = (float4*)(ws + 5016320);                            // zero range

  void* args[] = {
    (void*)&c0, (void*)&c1, (void*)&c2, (void*)&c3, (void*)&c4, (void*)&c5,
    (void*)&g0, (void*)&g1, (void*)&g2, (void*)&g3, (void*)&g4, (void*)&g5,
    (void*)&scores, (void*)&selkeys, (void*)&boxes, (void*)&oscore,
    (void*)&lab8, (void*)&obmax_u, (void*)&ghist, (void*)&ctrl,
    (void*)&eqg, (void*)&rank_part, (void*)&outp, (void*)&zbase
  };
  hipLaunchCooperativeKernel((const void*)k_mega, dim3(NBLK), dim3(256),
                             args, 0, stream);
}

// Round 9
// 223.951 us; speedup vs baseline: 1.3740x; 1.3740x over previous
//
#include <hip/hip_runtime.h>
#include <stdint.h>

#define NB 4
#define KTOT 5480
#define PER_IMG 258720
#define SCORE_THR 0.02f
#define IOU_THR 0.45f
#define REL_BASE 0x3CA3D70Bu   // smallest float bits > 0.02f
#define JCH 10                 // rank j-chunks
#define JSZ 548                // KTOT / JCH
#define ICH 22                 // rank i-chunks (256 keys each)
#define NMSCAP 512

__constant__ int cFEAT[6]    = {20,10,5,3,2,1};
__constant__ int cSTRIDE[6]  = {16,32,64,107,160,320};
__constant__ int cMIN[6]     = {48,100,150,202,253,304};
__constant__ int cMAX[6]     = {100,150,202,253,304,320};
__constant__ int cNFLAT[6]   = {192000,48000,12000,4320,1920,480};
__constant__ int cFLATOFF[6] = {0,192000,240000,252000,256320,258240};
__constant__ int cKSEL[6]    = {1000,1000,1000,1000,1000,480};
__constant__ int cKOFF[6]    = {0,1000,2000,3000,4000,5000};
__constant__ double cRATIO[6] = {1.0,1.0,0.5,2.0,1.0/3.0,3.0};

__device__ __forceinline__ unsigned long long mk_key(unsigned kb, int lev, unsigned idx) {
  return ((unsigned long long)kb << 21) |
         (unsigned long long)(0x1FFFFFu ^ (((unsigned)lev << 18) | idx));
}

__device__ __forceinline__ unsigned long long shfl64(unsigned long long x, int src) {
  int lo = __shfl((int)(unsigned)(x & 0xffffffffull), src);
  int hi = __shfl((int)(unsigned)(x >> 32), src);
  return ((unsigned long long)(unsigned)hi << 32) | (unsigned)lo;
}

// ---------------- K1: tiled softmax (coalesced via swizzled LDS), scores only ----
__global__ __launch_bounds__(256) void k_softmax(
    const float* __restrict__ c0, const float* __restrict__ c1,
    const float* __restrict__ c2, const float* __restrict__ c3,
    const float* __restrict__ c4, const float* __restrict__ c5,
    float* __restrict__ scores)
{
  int t = blockIdx.x;
  int b = t / 78, rem = t % 78;
  int lev, a, cb;
  if (rem < 42)      { lev = 0; a = rem / 7;         cb = (rem % 7) * 64; }
  else if (rem < 54) { lev = 1; a = (rem - 42) >> 1; cb = ((rem - 42) & 1) * 64; }
  else               { lev = 2 + (rem - 54) / 6; a = (rem - 54) % 6; cb = 0; }
  const float* cls = (lev==0)?c0:(lev==1)?c1:(lev==2)?c2:(lev==3)?c3:(lev==4)?c4:c5;
  int f = cFEAT[lev], ff = f * f;
  int ncell = ff - cb; if (ncell > 64) ncell = 64;

  __shared__ float tile[81 * 64];
  const float* base = cls + (size_t)(b * 486 + a * 81) * ff + cb;
  for (int t2 = threadIdx.x; t2 < 81 * 64; t2 += 256) {
    int c = t2 >> 6, cell = t2 & 63;
    if (cell < ncell)
      tile[(c << 6) | (cell ^ (c & 63))] = base[c * ff + cell];
  }
  __syncthreads();

  int lane = threadIdx.x & 63, w = threadIdx.x >> 6;
  for (int cell = w; cell < ncell; cell += 4) {
    float v1 = tile[(lane << 6) | (cell ^ lane)];
    float v2 = (lane <= 16) ? tile[((lane + 64) << 6) | (cell ^ lane)]
                            : __uint_as_float(0xff800000u);
    float mx = fmaxf(v1, v2);
    #pragma unroll
    for (int m = 32; m; m >>= 1) mx = fmaxf(mx, __shfl_xor(mx, m));
    float e1 = expf(v1 - mx);
    float e2 = (lane <= 16) ? expf(v2 - mx) : 0.f;
    float sm = e1 + e2;
    #pragma unroll
    for (int m = 32; m; m >>= 1) sm += __shfl_xor(sm, m);
    int row = (cb + cell) * 6 + a;
    float* out = scores + (size_t)b * PER_IMG + cFLATOFF[lev] + row * 80;
    float p1 = e1 / sm;
    out[lane] = (p1 > SCORE_THR) ? p1 : -1.f;
    if (lane < 16) {
      float p2 = e2 / sm;
      out[lane + 64] = (p2 > SCORE_THR) ? p2 : -1.f;
    }
  }
}

// ---------------- K2: per-task exact top-k with self LDS histogram ---------------
// One block per (img,level). Also zeroes obmax_u[4] + done2[88] (used by K3).
__global__ __launch_bounds__(1024) void k_select(
    const float* __restrict__ scores, unsigned long long* __restrict__ selkeys,
    unsigned* __restrict__ obmax_done)   // [0..3]=obmax, [4..91]=done2
{
  int task = blockIdx.x;
  int b = task / 6, lev = task % 6;
  int tid = threadIdx.x;
  int n = cNFLAT[lev];
  unsigned k = (unsigned)cKSEL[lev];
  const float* s = scores + (size_t)b * PER_IMG + cFLATOFF[lev];
  unsigned long long* out = selkeys + (size_t)b * KTOT + cKOFF[lev];
  unsigned levtag = (unsigned)lev << 18;

  if (task == 0 && tid < 92) obmax_done[tid] = 0;

  if (lev == 5) {  // keep all (k == n)
    for (int i = tid; i < n; i += 1024) {
      float v = s[i];
      unsigned kb = (v > SCORE_THR) ? __float_as_uint(v) : 0u;
      out[i] = mk_key(kb, lev, (unsigned)i);
    }
    return;
  }

  __shared__ union { unsigned hist[8192]; unsigned long long eqb[4096]; } u;
  __shared__ unsigned sc[1024];
  __shared__ unsigned sh_cnt, sh_eq, sh_b1, sh_byte, sh_r;

  // ---- pass A: LDS histogram ----
  for (int i = tid; i < 8192; i += 1024) u.hist[i] = 0;
  __syncthreads();
  {
    const float4* s4 = (const float4*)s;
    int n4 = n >> 2;
    #pragma unroll 4
    for (int i0 = tid; i0 < n4; i0 += 1024) {
      float4 vv = s4[i0];
      #pragma unroll
      for (int e = 0; e < 4; ++e) {
        float v = (e == 0) ? vv.x : (e == 1) ? vv.y : (e == 2) ? vv.z : vv.w;
        if (v > SCORE_THR)
          atomicAdd(&u.hist[(__float_as_uint(v) - REL_BASE) >> 13], 1u);
      }
    }
  }
  __syncthreads();

  // ---- suffix scan of 8192 bins ----
  unsigned loc[8];
  unsigned ssum = 0;
  #pragma unroll
  for (int j = 0; j < 8; ++j) { loc[j] = u.hist[tid * 8 + j]; ssum += loc[j]; }
  sc[tid] = ssum;
  __syncthreads();
  for (int off = 1; off < 1024; off <<= 1) {
    unsigned cur = sc[tid];
    unsigned add = (tid + off < 1024) ? sc[tid + off] : 0u;
    __syncthreads();
    sc[tid] = cur + add;
    __syncthreads();
  }
  unsigned c = sc[0];

  if (c >= k) {
    // ---- find cutoff bin b1 ----
    unsigned above = (tid == 1023) ? 0u : sc[tid + 1];
    unsigned run = above;
    #pragma unroll
    for (int j = 7; j >= 0; --j) {
      unsigned hj = loc[j];
      if (run < k && run + hj >= k) sh_b1 = (unsigned)(tid * 8 + j);
      run += hj;
    }
    if (tid == 0) { sh_cnt = 0; sh_eq = 0; }
    __syncthreads();           // hist no longer needed; eqb may alias now
    unsigned b1 = sh_b1;
    unsigned base_lo = REL_BASE + (b1 << 13);
    unsigned base_hi = base_lo + 8192u;

    // ---- pass B: emit winners (direct) + cutoff-bin ties (LDS) ----
    {
      const float4* s4 = (const float4*)s;
      int n4 = n >> 2;
      #pragma unroll 4
      for (int i0 = tid; i0 < n4; i0 += 1024) {
        float4 vv = s4[i0];
        #pragma unroll
        for (int e = 0; e < 4; ++e) {
          float v = (e == 0) ? vv.x : (e == 1) ? vv.y : (e == 2) ? vv.z : vv.w;
          if (v > SCORE_THR) {
            unsigned kb = __float_as_uint(v);
            unsigned idx = (unsigned)(i0 * 4 + e);
            if (kb >= base_hi) {
              unsigned slot = atomicAdd(&sh_cnt, 1u);
              out[slot] = mk_key(kb, lev, idx);
            } else if (kb >= base_lo) {
              unsigned p = atomicAdd(&sh_eq, 1u);
              if (p < 4096u) u.eqb[p] = mk_key(kb, lev, idx);
            }
          }
        }
      }
    }
    __syncthreads();
    unsigned cnt = sh_cnt;
    unsigned e = sh_eq;
    unsigned need = k - cnt;
    if (e <= 4096u) {
      if (e == need) {
        for (unsigned t = tid; t < need; t += 1024) out[cnt + t] = u.eqb[t];
      } else {
        unsigned P = 1; while (P < e) P <<= 1;
        for (unsigned t = tid; t < P; t += 1024) if (t >= e) u.eqb[t] = 0ull;
        __syncthreads();
        for (unsigned sz = 2; sz <= P; sz <<= 1)
          for (unsigned st = sz >> 1; st; st >>= 1) {
            for (unsigned w = tid; w < P / 2; w += 1024) {
              unsigned i = ((w & ~(st - 1)) << 1) | (w & (st - 1));
              unsigned l = i | st;
              bool up = ((i & sz) == 0);
              unsigned long long A = u.eqb[i], B = u.eqb[l];
              if ((A < B) == up) { u.eqb[i] = B; u.eqb[l] = A; }  // descending
            }
            __syncthreads();
          }
        for (unsigned t = tid; t < need; t += 1024) out[cnt + t] = u.eqb[t];
      }
      return;
    }

    // ---- pathological eq overflow: exact byte-radix slowpath ----
    unsigned* hist = sc;               // first 256 of scan buffer
    unsigned* equ = (unsigned*)u.eqb;  // u32 index buffer, cap 4096
    unsigned prefix = 0, r = k;
    for (int pass = 3; pass >= 0; --pass) {
      int shift = pass * 8;
      for (int i = tid; i < 256; i += 1024) hist[i] = 0;
      __syncthreads();
      for (int i = tid; i < n; i += 1024) {
        float v = s[i];
        unsigned kb = (v > SCORE_THR) ? __float_as_uint(v) : 0u;
        bool match = (pass == 3) || (((kb ^ prefix) >> (shift + 8)) == 0u);
        if (match) atomicAdd(&hist[(kb >> shift) & 255u], 1u);
      }
      __syncthreads();
      if (tid == 0) {
        unsigned cum = 0, byte = 0, rr = r;
        for (int bb = 255; bb >= 0; --bb) {
          unsigned hh = hist[bb];
          if (cum + hh >= r) { byte = (unsigned)bb; rr = r - cum; break; }
          cum += hh;
        }
        sh_byte = byte; sh_r = rr;
      }
      __syncthreads();
      prefix |= (sh_byte << shift);
      r = sh_r;
      __syncthreads();
    }
    unsigned Kstar = prefix;
    if (tid == 0) { sh_cnt = 0; sh_eq = 0; }
    __syncthreads();
    for (int i = tid; i < n; i += 1024) {
      float v = s[i];
      unsigned kb = (v > SCORE_THR) ? __float_as_uint(v) : 0u;
      if (kb > Kstar) {
        unsigned slot = atomicAdd(&sh_cnt, 1u);
        out[slot] = mk_key(kb, lev, (unsigned)i);
      } else if (kb == Kstar) {
        unsigned es = atomicAdd(&sh_eq, 1u);
        if (es < 4096u) equ[es] = (unsigned)i;
      }
    }
    __syncthreads();
    unsigned m = sh_cnt;
    unsigned e2 = (sh_eq < 4096u) ? sh_eq : 4096u;
    unsigned need2 = k - m;
    if (e2 > need2) {
      unsigned P = 1; while (P < e2) P <<= 1;
      for (unsigned t = tid; t < P; t += 1024) if (t >= e2) equ[t] = 0xFFFFFFFFu;
      __syncthreads();
      for (unsigned sz = 2; sz <= P; sz <<= 1)
        for (unsigned st = sz >> 1; st; st >>= 1) {
          for (unsigned w = tid; w < P / 2; w += 1024) {
            unsigned i = ((w & ~(st - 1)) << 1) | (w & (st - 1));
            unsigned l = i | st;
            bool up = ((i & sz) == 0);
            unsigned A = equ[i], B = equ[l];
            if ((A > B) == up) { equ[i] = B; equ[l] = A; }  // ascending
          }
          __syncthreads();
        }
    }
    __syncthreads();
    for (unsigned t = tid; t < need2; t += 1024)
      out[m + t] = ((unsigned long long)Kstar << 21) |
                   (unsigned long long)(0x1FFFFFu ^ (levtag | equ[t]));
    return;
  }

  // ---- mode 1: fewer candidates than k — all candidates + ordered fillers ----
  if (tid == 0) sh_cnt = 0;
  __syncthreads();
  {
    const float4* s4 = (const float4*)s;
    int n4 = n >> 2;
    #pragma unroll 4
    for (int i0 = tid; i0 < n4; i0 += 1024) {
      float4 vv = s4[i0];
      #pragma unroll
      for (int e = 0; e < 4; ++e) {
        float v = (e == 0) ? vv.x : (e == 1) ? vv.y : (e == 2) ? vv.z : vv.w;
        if (v > SCORE_THR) {
          unsigned slot = atomicAdd(&sh_cnt, 1u);
          out[slot] = mk_key(__float_as_uint(v), lev, (unsigned)(i0 * 4 + e));
        }
      }
    }
  }
  __syncthreads();
  unsigned need = k - c;
  unsigned base = 0;
  for (int start = 0; start < n && base < need; start += 1024) {
    int i = start + tid;
    unsigned pred = (i < n && !(s[i] > SCORE_THR)) ? 1u : 0u;
    sc[tid] = pred;
    __syncthreads();
    for (int off = 1; off < 1024; off <<= 1) {
      unsigned add = (tid >= off) ? sc[tid - off] : 0u;
      unsigned v = sc[tid];
      __syncthreads();
      sc[tid] = v + add;
      __syncthreads();
    }
    unsigned incl = sc[tid];
    unsigned total = sc[1023];
    unsigned excl = incl - pred;
    if (pred && (base + excl) < need)
      out[c + base + excl] =
          (unsigned long long)(0x1FFFFFu ^ (levtag | (unsigned)i));
    __syncthreads();
    base += total;
  }
}

// ---------------- K3: partitioned rank; last j-block decodes ---------------------
__global__ __launch_bounds__(256) void k_rankdec(
    const unsigned long long* __restrict__ selkeys, unsigned* rank_part,
    const float* __restrict__ g0, const float* __restrict__ g1,
    const float* __restrict__ g2, const float* __restrict__ g3,
    const float* __restrict__ g4, const float* __restrict__ g5,
    float* __restrict__ boxes, float* __restrict__ oscore,
    unsigned char* __restrict__ lab8, unsigned* obmax_done,
    float* __restrict__ outp)
{
  int blk = blockIdx.x;
  int jc = blk % JCH;
  int g = blk / JCH;           // g = b*ICH + ic, 0..87
  int ic = g % ICH, b = g / ICH;
  int tid = threadIdx.x;
  int i = ic * 256 + tid;

  __shared__ __align__(16) unsigned long long sk[JSZ];
  __shared__ double ba[6][6][4];
  __shared__ int slast;

  const unsigned long long* keys = selkeys + (size_t)b * KTOT;
  for (int j = tid; j < JSZ; j += 256) sk[j] = keys[jc * JSZ + j];
  unsigned long long mk = (i < KTOT) ? keys[i] : 0ull;
  __syncthreads();
  unsigned rpart = 0;
  const ulonglong2* sk2 = (const ulonglong2*)sk;
  #pragma unroll 8
  for (int j = 0; j < JSZ / 2; ++j) {
    ulonglong2 kk = sk2[j];
    rpart += (kk.x > mk) ? 1u : 0u;
    rpart += (kk.y > mk) ? 1u : 0u;
  }
  if (i < KTOT) rank_part[((size_t)jc * NB + b) * KTOT + i] = rpart;

  __threadfence();             // release partials (agent scope, cross-XCD)
  if (tid == 0) {
    unsigned ret = atomicAdd(&obmax_done[4 + g], 1u);
    slast = (ret == JCH - 1);
  }
  __syncthreads();
  if (!slast) return;
  __threadfence();             // acquire other blocks' partials

  if (tid < 36) {
    int lev = tid / 6, a = tid % 6;
    double base = (double)cMIN[lev];
    double scl = (a == 1) ? sqrt((double)cMAX[lev] / (double)cMIN[lev]) : 1.0;
    double hr = sqrt(cRATIO[a]);
    double wr = 1.0 / hr;
    double wsz = base * scl * wr;
    double hsz = base * scl * hr;
    double cc = (double)cSTRIDE[lev] / 2.0;
    ba[lev][a][0] = cc - 0.5 * wsz;
    ba[lev][a][1] = cc - 0.5 * hsz;
    ba[lev][a][2] = cc + 0.5 * wsz;
    ba[lev][a][3] = cc + 0.5 * hsz;
  }
  __syncthreads();

  float lmax = 0.f;
  if (i < KTOT) {
    unsigned r = 0;
    #pragma unroll
    for (int jc2 = 0; jc2 < JCH; ++jc2)
      r += rank_part[((size_t)jc2 * NB + b) * KTOT + i];
    unsigned tag = 0x1FFFFFu ^ (unsigned)(mk & 0x1FFFFFull);
    int lev = tag >> 18;
    int fi = tag & 0x3FFFF;
    unsigned vb2 = (unsigned)(mk >> 21);
    int valid = (vb2 != 0u);
    float score = valid ? __uint_as_float(vb2) : 0.f;
    int label = fi % 80;
    int arow = fi / 80;
    int a = arow % 6, cell = arow / 6;
    int f = cFEAT[lev], ff = f * f;
    int x = cell % f, y = cell / f;
    const float* gb = (lev==0)?g0:(lev==1)?g1:(lev==2)?g2:(lev==3)?g3:(lev==4)?g4:g5;
    const float* pb = gb + (size_t)(b * 24 + a * 4) * ff + y * f + x;
    float d0 = pb[0] * 0.1f, d1 = pb[ff] * 0.1f;
    float d2 = pb[2 * ff] * 0.2f, d3 = pb[3 * ff] * 0.2f;
    const float MR = (float)4.135166556742356;
    d2 = fminf(fmaxf(d2, -MR), MR);
    d3 = fminf(fmaxf(d3, -MR), MR);
    double shx = (double)(x * cSTRIDE[lev]);
    double shy = (double)(y * cSTRIDE[lev]);
    float p0 = (float)(ba[lev][a][0] + shx);
    float p1 = (float)(ba[lev][a][1] + shy);
    float p2 = (float)(ba[lev][a][2] + shx);
    float p3 = (float)(ba[lev][a][3] + shy);
    float pxc = (p0 + p2) * 0.5f, pyc = (p1 + p3) * 0.5f;
    float pw = p2 - p0, ph = p3 - p1;
    float gx = pxc + pw * d0, gy = pyc + ph * d1;
    float gw = pw * expf(d2), gh = ph * expf(d3);
    float x1 = gx - 0.5f * gw, y1 = gy - 0.5f * gh;
    float x2 = gx + 0.5f * gw, y2 = gy + 0.5f * gh;
    x1 = fminf(fmaxf(x1, 0.f), 320.f);
    y1 = fminf(fmaxf(y1, 0.f), 320.f);
    x2 = fminf(fmaxf(x2, 0.f), 320.f);
    y2 = fminf(fmaxf(y2, 0.f), 320.f);
    size_t o = (size_t)b * KTOT + (size_t)r;
    boxes[o * 4 + 0] = x1; boxes[o * 4 + 1] = y1;
    boxes[o * 4 + 2] = x2; boxes[o * 4 + 3] = y2;
    oscore[o] = score;
    lab8[o] = valid ? (unsigned char)label : (unsigned char)0xFF;
    outp[(size_t)NB * KTOT * 5 + o] = (float)label;
    if (!valid) {
      float* det = outp + o * 5;
      det[0] = 0.f; det[1] = 0.f; det[2] = 0.f; det[3] = 0.f; det[4] = 0.f;
      outp[(size_t)NB * KTOT * 6 + o] = 0.f;
    }
    lmax = fmaxf(fmaxf(x1, y1), fmaxf(x2, y2));
  }
  #pragma unroll
  for (int m = 32; m; m >>= 1) lmax = fmaxf(lmax, __shfl_xor(lmax, m));
  if ((tid & 63) == 0) atomicMax(&obmax_done[b], __float_as_uint(lmax));
}

// ---------------- K4: mask-matrix NMS, one block per (image,class) ---------------
__global__ __launch_bounds__(256) void k_nms(
    const float* __restrict__ boxes, const float* __restrict__ oscore,
    const unsigned char* __restrict__ lab8, const unsigned* __restrict__ obmax_done,
    float* __restrict__ out)
{
  int blk = blockIdx.x;
  int b = blk / 80, cls = blk % 80;
  int tid = threadIdx.x;
  int lane = tid & 63, w = tid >> 6;

  __shared__ unsigned short list[NMSCAP];
  __shared__ float ox1[NMSCAP], oy1[NMSCAP], ox2[NMSCAP], oy2[NMSCAP];
  __shared__ float oar[NMSCAP], osc[NMSCAP];
  __shared__ float rx1[NMSCAP], ry1[NMSCAP], rx2[NMSCAP], ry2[NMSCAP];
  __shared__ unsigned long long mask[NMSCAP][8];
  __shared__ unsigned ccnt[24], cbase[24];
  __shared__ int sh_n;
  __shared__ unsigned long long alive_s[8];

  float ofs = (float)cls * (__uint_as_float(obmax_done[b]) + 1.0f);
  const unsigned* lb32 = (const unsigned*)(lab8 + (size_t)b * KTOT);

  unsigned long long balA[6][4];
  #pragma unroll
  for (int ci = 0; ci < 6; ++ci) {
    int chunk = w + ci * 4;
    unsigned v = 0xFFFFFFFFu;
    if (chunk < 22) {
      int u = chunk * 64 + lane;
      if (u < KTOT / 4) v = lb32[u];
    }
    unsigned long long m0 = __ballot(((v      ) & 0xFFu) == (unsigned)cls);
    unsigned long long m1 = __ballot(((v >>  8) & 0xFFu) == (unsigned)cls);
    unsigned long long m2 = __ballot(((v >> 16) & 0xFFu) == (unsigned)cls);
    unsigned long long m3 = __ballot(((v >> 24) & 0xFFu) == (unsigned)cls);
    balA[ci][0] = m0; balA[ci][1] = m1; balA[ci][2] = m2; balA[ci][3] = m3;
    if (chunk < 22 && lane == 0)
      ccnt[chunk] = (unsigned)(__popcll(m0) + __popcll(m1) + __popcll(m2) + __popcll(m3));
  }
  __syncthreads();
  if (tid == 0) {
    unsigned tot = 0;
    for (int c = 0; c < 22; ++c) { cbase[c] = tot; tot += ccnt[c]; }
    sh_n = (tot < NMSCAP) ? (int)tot : NMSCAP;
  }
  __syncthreads();
  int n = sh_n;
  unsigned long long blt = (lane == 0) ? 0ull : ((~0ull) >> (64 - lane));
  #pragma unroll
  for (int ci = 0; ci < 6; ++ci) {
    int chunk = w + ci * 4;
    if (chunk < 22) {
      unsigned pos = cbase[chunk];
      unsigned below = (unsigned)(__popcll(balA[ci][0] & blt) + __popcll(balA[ci][1] & blt) +
                                  __popcll(balA[ci][2] & blt) + __popcll(balA[ci][3] & blt));
      unsigned within = 0;
      #pragma unroll
      for (int k = 0; k < 4; ++k) {
        if ((balA[ci][k] >> lane) & 1ull) {
          unsigned mypos = pos + below + within;
          if (mypos < NMSCAP) list[mypos] = (unsigned short)(chunk * 256 + lane * 4 + k);
          ++within;
        }
      }
    }
  }
  __syncthreads();

  for (int t = tid; t < n; t += 256) {
    int pos = list[t];
    size_t o = (size_t)b * KTOT + pos;
    float4 bb = *(const float4*)(boxes + o * 4);
    rx1[t] = bb.x; ry1[t] = bb.y; rx2[t] = bb.z; ry2[t] = bb.w;
    float a1 = bb.x + ofs, b1 = bb.y + ofs, a2 = bb.z + ofs, b2 = bb.w + ofs;
    ox1[t] = a1; oy1[t] = b1; ox2[t] = a2; oy2[t] = b2;
    oar[t] = (a2 - a1) * (b2 - b1);
    osc[t] = oscore[o];
  }
  __syncthreads();

  int nw = (n + 63) >> 6;
  for (int i = tid; i < n; i += 256) {
    float ax1 = ox1[i], ay1 = oy1[i], ax2 = ox2[i], ay2 = oy2[i], aar = oar[i];
    int w0 = i >> 6;
    for (int wd = w0; wd < nw; ++wd) {
      unsigned long long m = 0;
      int jbase = wd << 6;
      int jend = n - jbase; if (jend > 64) jend = 64;
      for (int jj = 0; jj < jend; ++jj) {
        int j = jbase + jj;
        if (j > i) {
          float ix1 = fmaxf(ax1, ox1[j]);
          float iy1 = fmaxf(ay1, oy1[j]);
          float ix2 = fminf(ax2, ox2[j]);
          float iy2 = fminf(ay2, oy2[j]);
          float iw = fmaxf(ix2 - ix1, 0.f);
          float ih = fmaxf(iy2 - iy1, 0.f);
          float inter = iw * ih;
          float iou = inter / (aar + oar[j] - inter);
          if (iou > IOU_THR) m |= (1ull << jj);
        }
      }
      mask[i][wd] = m;
    }
  }
  __syncthreads();

  if (w == 0) {
    unsigned long long aw = 0;
    if (lane < nw) {
      int rem = n - (lane << 6);
      aw = (rem >= 64) ? ~0ull : ((1ull << rem) - 1ull);
    }
    for (int i = 0; i < n; ++i) {
      int wi = i >> 6;
      unsigned long long mrow = (lane >= wi && lane < nw) ? mask[i][lane] : 0ull;
      unsigned long long tw = shfl64(aw, wi);
      if ((tw >> (i & 63)) & 1ull) aw &= ~mrow;
    }
    if (lane < 8) alive_s[lane] = aw;
  }
  __syncthreads();

  for (int t = tid; t < n; t += 256) {
    float kf = ((alive_s[t >> 6] >> (t & 63)) & 1ull) ? 1.f : 0.f;
    int pos = list[t];
    size_t o = (size_t)b * KTOT + pos;
    float* det = out + o * 5;
    det[0] = rx1[t] * kf; det[1] = ry1[t] * kf;
    det[2] = rx2[t] * kf; det[3] = ry2[t] * kf;
    det[4] = osc[t] * kf;
    out[(size_t)NB * KTOT * 6 + o] = kf;
  }
}

extern "C" void kernel_launch(void* const* d_in, const int* in_sizes, int n_in,
                              void* d_out, int out_size, void* d_ws, size_t ws_size,
                              hipStream_t stream) {
  (void)in_sizes; (void)n_in; (void)out_size; (void)ws_size;
  const float* cls[6]; const float* bbx[6];
  for (int i = 0; i < 6; ++i) {
    cls[i] = (const float*)d_in[2 * i];
    bbx[i] = (const float*)d_in[2 * i + 1];
  }
  char* ws = (char*)d_ws;
  float* scores = (float*)ws;                                         // 4,139,520
  unsigned* rank_part = (unsigned*)ws;                                // aliases scores (dead after select)
  unsigned long long* selkeys = (unsigned long long*)(ws + 4139520);  // 175,360
  float* boxes  = (float*)(ws + 4314880);                             // 350,720
  float* oscore = (float*)(ws + 4665600);                             // 87,680
  unsigned char* lab8 = (unsigned char*)(ws + 4753280);               // 21,920
  unsigned* obmax_done = (unsigned*)(ws + 5016320);                   // [0..3]=obmax,[4..91]=done2

  k_softmax<<<NB * 78, 256, 0, stream>>>(cls[0], cls[1], cls[2], cls[3], cls[4], cls[5],
                                         scores);
  k_select<<<NB * 6, 1024, 0, stream>>>(scores, selkeys, obmax_done);
  k_rankdec<<<NB * ICH * JCH, 256, 0, stream>>>(selkeys, rank_part, bbx[0], bbx[1],
                                                bbx[2], bbx[3], bbx[4], bbx[5], boxes,
                                                oscore, lab8, obmax_done, (float*)d_out);
  k_nms<<<NB * 80, 256, 0, stream>>>(boxes, oscore, lab8, obmax_done, (float*)d_out);
}

// Round 10
// 117.055 us; speedup vs baseline: 2.6288x; 1.9132x over previous
//
#include <hip/hip_runtime.h>
#include <stdint.h>

#define NB 4
#define KTOT 5480
#define PER_IMG 258720
#define SCORE_THR 0.02f
#define IOU_THR 0.45f
#define REL_BASE 0x3CA3D70Bu   // smallest float bits > 0.02f
#define JCH 10                 // rank j-chunks
#define JSZ 548                // KTOT / JCH
#define ICH 11                 // rank/decode i-chunks (512 keys each)
#define NMSCAP 512

__constant__ int cFEAT[6]    = {20,10,5,3,2,1};
__constant__ int cSTRIDE[6]  = {16,32,64,107,160,320};
__constant__ int cMIN[6]     = {48,100,150,202,253,304};
__constant__ int cMAX[6]     = {100,150,202,253,304,320};
__constant__ int cNFLAT[6]   = {192000,48000,12000,4320,1920,480};
__constant__ int cFLATOFF[6] = {0,192000,240000,252000,256320,258240};
__constant__ int cKSEL[6]    = {1000,1000,1000,1000,1000,480};
__constant__ int cKOFF[6]    = {0,1000,2000,3000,4000,5000};
__constant__ double cRATIO[6] = {1.0,1.0,0.5,2.0,1.0/3.0,3.0};

__device__ __forceinline__ unsigned long long mk_key(unsigned kb, int lev, unsigned idx) {
  return ((unsigned long long)kb << 21) |
         (unsigned long long)(0x1FFFFFu ^ (((unsigned)lev << 18) | idx));
}

__device__ __forceinline__ unsigned long long shfl64(unsigned long long x, int src) {
  int lo = __shfl((int)(unsigned)(x & 0xffffffffull), src);
  int hi = __shfl((int)(unsigned)(x >> 32), src);
  return ((unsigned long long)(unsigned)hi << 32) | (unsigned)lo;
}

// ---------------- K1: tiled softmax (coalesced via swizzled LDS), scores only ----
// Block 0 also zeroes obmax[0..3] (consumed 2 kernel-boundaries later).
__global__ __launch_bounds__(256) void k_softmax(
    const float* __restrict__ c0, const float* __restrict__ c1,
    const float* __restrict__ c2, const float* __restrict__ c3,
    const float* __restrict__ c4, const float* __restrict__ c5,
    float* __restrict__ scores, unsigned* __restrict__ obmax_u)
{
  int t = blockIdx.x;
  if (t == 0 && threadIdx.x < 4) obmax_u[threadIdx.x] = 0u;
  int b = t / 78, rem = t % 78;
  int lev, a, cb;
  if (rem < 42)      { lev = 0; a = rem / 7;         cb = (rem % 7) * 64; }
  else if (rem < 54) { lev = 1; a = (rem - 42) >> 1; cb = ((rem - 42) & 1) * 64; }
  else               { lev = 2 + (rem - 54) / 6; a = (rem - 54) % 6; cb = 0; }
  const float* cls = (lev==0)?c0:(lev==1)?c1:(lev==2)?c2:(lev==3)?c3:(lev==4)?c4:c5;
  int f = cFEAT[lev], ff = f * f;
  int ncell = ff - cb; if (ncell > 64) ncell = 64;

  __shared__ float tile[81 * 64];
  const float* base = cls + (size_t)(b * 486 + a * 81) * ff + cb;
  for (int t2 = threadIdx.x; t2 < 81 * 64; t2 += 256) {
    int c = t2 >> 6, cell = t2 & 63;
    if (cell < ncell)
      tile[(c << 6) | (cell ^ (c & 63))] = base[c * ff + cell];
  }
  __syncthreads();

  int lane = threadIdx.x & 63, w = threadIdx.x >> 6;
  for (int cell = w; cell < ncell; cell += 4) {
    float v1 = tile[(lane << 6) | (cell ^ lane)];
    float v2 = (lane <= 16) ? tile[((lane + 64) << 6) | (cell ^ lane)]
                            : __uint_as_float(0xff800000u);
    float mx = fmaxf(v1, v2);
    #pragma unroll
    for (int m = 32; m; m >>= 1) mx = fmaxf(mx, __shfl_xor(mx, m));
    float e1 = expf(v1 - mx);
    float e2 = (lane <= 16) ? expf(v2 - mx) : 0.f;
    float sm = e1 + e2;
    #pragma unroll
    for (int m = 32; m; m >>= 1) sm += __shfl_xor(sm, m);
    int row = (cb + cell) * 6 + a;
    float* out = scores + (size_t)b * PER_IMG + cFLATOFF[lev] + row * 80;
    float p1 = e1 / sm;
    out[lane] = (p1 > SCORE_THR) ? p1 : -1.f;
    if (lane < 16) {
      float p2 = e2 / sm;
      out[lane + 64] = (p2 > SCORE_THR) ? p2 : -1.f;
    }
  }
}

// ---------------- K2: per-task exact top-k with self LDS histogram ---------------
__global__ __launch_bounds__(1024) void k_select(
    const float* __restrict__ scores, unsigned long long* __restrict__ selkeys)
{
  int task = blockIdx.x;
  int b = task / 6, lev = task % 6;
  int tid = threadIdx.x;
  int n = cNFLAT[lev];
  unsigned k = (unsigned)cKSEL[lev];
  const float* s = scores + (size_t)b * PER_IMG + cFLATOFF[lev];
  unsigned long long* out = selkeys + (size_t)b * KTOT + cKOFF[lev];
  unsigned levtag = (unsigned)lev << 18;

  if (lev == 5) {  // keep all (k == n)
    for (int i = tid; i < n; i += 1024) {
      float v = s[i];
      unsigned kb = (v > SCORE_THR) ? __float_as_uint(v) : 0u;
      out[i] = mk_key(kb, lev, (unsigned)i);
    }
    return;
  }

  __shared__ union { unsigned hist[8192]; unsigned long long eqb[4096]; } u;
  __shared__ unsigned sc[1024];
  __shared__ unsigned sh_cnt, sh_eq, sh_b1, sh_byte, sh_r;

  // ---- pass A: LDS histogram ----
  for (int i = tid; i < 8192; i += 1024) u.hist[i] = 0;
  __syncthreads();
  {
    const float4* s4 = (const float4*)s;
    int n4 = n >> 2;
    #pragma unroll 4
    for (int i0 = tid; i0 < n4; i0 += 1024) {
      float4 vv = s4[i0];
      #pragma unroll
      for (int e = 0; e < 4; ++e) {
        float v = (e == 0) ? vv.x : (e == 1) ? vv.y : (e == 2) ? vv.z : vv.w;
        if (v > SCORE_THR)
          atomicAdd(&u.hist[(__float_as_uint(v) - REL_BASE) >> 13], 1u);
      }
    }
  }
  __syncthreads();

  // ---- suffix scan of 8192 bins ----
  unsigned loc[8];
  unsigned ssum = 0;
  #pragma unroll
  for (int j = 0; j < 8; ++j) { loc[j] = u.hist[tid * 8 + j]; ssum += loc[j]; }
  sc[tid] = ssum;
  __syncthreads();
  for (int off = 1; off < 1024; off <<= 1) {
    unsigned cur = sc[tid];
    unsigned add = (tid + off < 1024) ? sc[tid + off] : 0u;
    __syncthreads();
    sc[tid] = cur + add;
    __syncthreads();
  }
  unsigned c = sc[0];

  if (c >= k) {
    unsigned above = (tid == 1023) ? 0u : sc[tid + 1];
    unsigned run = above;
    #pragma unroll
    for (int j = 7; j >= 0; --j) {
      unsigned hj = loc[j];
      if (run < k && run + hj >= k) sh_b1 = (unsigned)(tid * 8 + j);
      run += hj;
    }
    if (tid == 0) { sh_cnt = 0; sh_eq = 0; }
    __syncthreads();           // hist dead; eqb may alias now
    unsigned b1 = sh_b1;
    unsigned base_lo = REL_BASE + (b1 << 13);
    unsigned base_hi = base_lo + 8192u;

    // ---- pass B: emit winners (direct) + cutoff-bin ties (LDS) ----
    {
      const float4* s4 = (const float4*)s;
      int n4 = n >> 2;
      #pragma unroll 4
      for (int i0 = tid; i0 < n4; i0 += 1024) {
        float4 vv = s4[i0];
        #pragma unroll
        for (int e = 0; e < 4; ++e) {
          float v = (e == 0) ? vv.x : (e == 1) ? vv.y : (e == 2) ? vv.z : vv.w;
          if (v > SCORE_THR) {
            unsigned kb = __float_as_uint(v);
            unsigned idx = (unsigned)(i0 * 4 + e);
            if (kb >= base_hi) {
              unsigned slot = atomicAdd(&sh_cnt, 1u);
              out[slot] = mk_key(kb, lev, idx);
            } else if (kb >= base_lo) {
              unsigned p = atomicAdd(&sh_eq, 1u);
              if (p < 4096u) u.eqb[p] = mk_key(kb, lev, idx);
            }
          }
        }
      }
    }
    __syncthreads();
    unsigned cnt = sh_cnt;
    unsigned e = sh_eq;
    unsigned need = k - cnt;
    if (e <= 4096u) {
      if (e == need) {
        for (unsigned t = tid; t < need; t += 1024) out[cnt + t] = u.eqb[t];
      } else {
        unsigned P = 1; while (P < e) P <<= 1;
        for (unsigned t = tid; t < P; t += 1024) if (t >= e) u.eqb[t] = 0ull;
        __syncthreads();
        for (unsigned sz = 2; sz <= P; sz <<= 1)
          for (unsigned st = sz >> 1; st; st >>= 1) {
            for (unsigned w = tid; w < P / 2; w += 1024) {
              unsigned i = ((w & ~(st - 1)) << 1) | (w & (st - 1));
              unsigned l = i | st;
              bool up = ((i & sz) == 0);
              unsigned long long A = u.eqb[i], B = u.eqb[l];
              if ((A < B) == up) { u.eqb[i] = B; u.eqb[l] = A; }  // descending
            }
            __syncthreads();
          }
        for (unsigned t = tid; t < need; t += 1024) out[cnt + t] = u.eqb[t];
      }
      return;
    }

    // ---- pathological eq overflow: exact byte-radix slowpath ----
    unsigned* hist = sc;
    unsigned* equ = (unsigned*)u.eqb;
    unsigned prefix = 0, r = k;
    for (int pass = 3; pass >= 0; --pass) {
      int shift = pass * 8;
      for (int i = tid; i < 256; i += 1024) hist[i] = 0;
      __syncthreads();
      for (int i = tid; i < n; i += 1024) {
        float v = s[i];
        unsigned kb = (v > SCORE_THR) ? __float_as_uint(v) : 0u;
        bool match = (pass == 3) || (((kb ^ prefix) >> (shift + 8)) == 0u);
        if (match) atomicAdd(&hist[(kb >> shift) & 255u], 1u);
      }
      __syncthreads();
      if (tid == 0) {
        unsigned cum = 0, byte = 0, rr = r;
        for (int bb = 255; bb >= 0; --bb) {
          unsigned hh = hist[bb];
          if (cum + hh >= r) { byte = (unsigned)bb; rr = r - cum; break; }
          cum += hh;
        }
        sh_byte = byte; sh_r = rr;
      }
      __syncthreads();
      prefix |= (sh_byte << shift);
      r = sh_r;
      __syncthreads();
    }
    unsigned Kstar = prefix;
    if (tid == 0) { sh_cnt = 0; sh_eq = 0; }
    __syncthreads();
    for (int i = tid; i < n; i += 1024) {
      float v = s[i];
      unsigned kb = (v > SCORE_THR) ? __float_as_uint(v) : 0u;
      if (kb > Kstar) {
        unsigned slot = atomicAdd(&sh_cnt, 1u);
        out[slot] = mk_key(kb, lev, (unsigned)i);
      } else if (kb == Kstar) {
        unsigned es = atomicAdd(&sh_eq, 1u);
        if (es < 4096u) equ[es] = (unsigned)i;
      }
    }
    __syncthreads();
    unsigned m = sh_cnt;
    unsigned e2 = (sh_eq < 4096u) ? sh_eq : 4096u;
    unsigned need2 = k - m;
    if (e2 > need2) {
      unsigned P = 1; while (P < e2) P <<= 1;
      for (unsigned t = tid; t < P; t += 1024) if (t >= e2) equ[t] = 0xFFFFFFFFu;
      __syncthreads();
      for (unsigned sz = 2; sz <= P; sz <<= 1)
        for (unsigned st = sz >> 1; st; st >>= 1) {
          for (unsigned w = tid; w < P / 2; w += 1024) {
            unsigned i = ((w & ~(st - 1)) << 1) | (w & (st - 1));
            unsigned l = i | st;
            bool up = ((i & sz) == 0);
            unsigned A = equ[i], B = equ[l];
            if ((A > B) == up) { equ[i] = B; equ[l] = A; }  // ascending
          }
          __syncthreads();
        }
    }
    __syncthreads();
    for (unsigned t = tid; t < need2; t += 1024)
      out[m + t] = ((unsigned long long)Kstar << 21) |
                   (unsigned long long)(0x1FFFFFu ^ (levtag | equ[t]));
    return;
  }

  // ---- mode 1: fewer candidates than k — all candidates + ordered fillers ----
  if (tid == 0) sh_cnt = 0;
  __syncthreads();
  {
    const float4* s4 = (const float4*)s;
    int n4 = n >> 2;
    #pragma unroll 4
    for (int i0 = tid; i0 < n4; i0 += 1024) {
      float4 vv = s4[i0];
      #pragma unroll
      for (int e = 0; e < 4; ++e) {
        float v = (e == 0) ? vv.x : (e == 1) ? vv.y : (e == 2) ? vv.z : vv.w;
        if (v > SCORE_THR) {
          unsigned slot = atomicAdd(&sh_cnt, 1u);
          out[slot] = mk_key(__float_as_uint(v), lev, (unsigned)(i0 * 4 + e));
        }
      }
    }
  }
  __syncthreads();
  unsigned need = k - c;
  unsigned base = 0;
  for (int start = 0; start < n && base < need; start += 1024) {
    int i = start + tid;
    unsigned pred = (i < n && !(s[i] > SCORE_THR)) ? 1u : 0u;
    sc[tid] = pred;
    __syncthreads();
    for (int off = 1; off < 1024; off <<= 1) {
      unsigned add = (tid >= off) ? sc[tid - off] : 0u;
      unsigned v = sc[tid];
      __syncthreads();
      sc[tid] = v + add;
      __syncthreads();
    }
    unsigned incl = sc[tid];
    unsigned total = sc[1023];
    unsigned excl = incl - pred;
    if (pred && (base + excl) < need)
      out[c + base + excl] =
          (unsigned long long)(0x1FFFFFu ^ (levtag | (unsigned)i));
    __syncthreads();
    base += total;
  }
}

// ---------------- K3a: partitioned O(N^2) rank (fence-free) ----------------------
__global__ __launch_bounds__(512) void k_rank(
    const unsigned long long* __restrict__ selkeys, unsigned* __restrict__ rank_part)
{
  int blk = blockIdx.x;
  int jc = blk % JCH;
  int rest = blk / JCH;
  int ic = rest % ICH, b = rest / ICH;
  int tid = threadIdx.x;
  __shared__ __align__(16) unsigned long long sk[JSZ];
  const unsigned long long* keys = selkeys + (size_t)b * KTOT;
  for (int j = tid; j < JSZ; j += 512) sk[j] = keys[jc * JSZ + j];
  int i = ic * 512 + tid;
  unsigned long long mk = (i < KTOT) ? keys[i] : 0ull;
  __syncthreads();
  unsigned r = 0;
  const ulonglong2* sk2 = (const ulonglong2*)sk;
  #pragma unroll 8
  for (int j = 0; j < JSZ / 2; ++j) {
    ulonglong2 kk = sk2[j];
    r += (kk.x > mk) ? 1u : 0u;
    r += (kk.y > mk) ? 1u : 0u;
  }
  if (i < KTOT) rank_part[((size_t)jc * NB + b) * KTOT + i] = r;
}

// ---------------- K3b: sum partials + decode + scatter ---------------------------
__global__ __launch_bounds__(512) void k_decode(
    const unsigned long long* __restrict__ selkeys, const unsigned* __restrict__ rank_part,
    const float* __restrict__ g0, const float* __restrict__ g1,
    const float* __restrict__ g2, const float* __restrict__ g3,
    const float* __restrict__ g4, const float* __restrict__ g5,
    float* __restrict__ boxes, float* __restrict__ oscore,
    unsigned char* __restrict__ lab8, unsigned* __restrict__ obmax_u,
    float* __restrict__ outp)
{
  int b = blockIdx.x / ICH, ic = blockIdx.x % ICH;
  int tid = threadIdx.x;
  int i = ic * 512 + tid;
  __shared__ double ba[6][6][4];
  if (tid < 36) {
    int lev = tid / 6, a = tid % 6;
    double base = (double)cMIN[lev];
    double scl = (a == 1) ? sqrt((double)cMAX[lev] / (double)cMIN[lev]) : 1.0;
    double hr = sqrt(cRATIO[a]);
    double wr = 1.0 / hr;
    double wsz = base * scl * wr;
    double hsz = base * scl * hr;
    double cc = (double)cSTRIDE[lev] / 2.0;
    ba[lev][a][0] = cc - 0.5 * wsz;
    ba[lev][a][1] = cc - 0.5 * hsz;
    ba[lev][a][2] = cc + 0.5 * wsz;
    ba[lev][a][3] = cc + 0.5 * hsz;
  }
  __syncthreads();

  float lmax = 0.f;
  if (i < KTOT) {
    unsigned long long mk = selkeys[(size_t)b * KTOT + i];
    unsigned r = 0;
    #pragma unroll
    for (int jc = 0; jc < JCH; ++jc)
      r += rank_part[((size_t)jc * NB + b) * KTOT + i];
    unsigned tag = 0x1FFFFFu ^ (unsigned)(mk & 0x1FFFFFull);
    int lev = tag >> 18;
    int fi = tag & 0x3FFFF;
    unsigned vb2 = (unsigned)(mk >> 21);
    int valid = (vb2 != 0u);
    float score = valid ? __uint_as_float(vb2) : 0.f;
    int label = fi % 80;
    int arow = fi / 80;
    int a = arow % 6, cell = arow / 6;
    int f = cFEAT[lev], ff = f * f;
    int x = cell % f, y = cell / f;
    const float* gb = (lev==0)?g0:(lev==1)?g1:(lev==2)?g2:(lev==3)?g3:(lev==4)?g4:g5;
    const float* pb = gb + (size_t)(b * 24 + a * 4) * ff + y * f + x;
    float d0 = pb[0] * 0.1f, d1 = pb[ff] * 0.1f;
    float d2 = pb[2 * ff] * 0.2f, d3 = pb[3 * ff] * 0.2f;
    const float MR = (float)4.135166556742356;
    d2 = fminf(fmaxf(d2, -MR), MR);
    d3 = fminf(fmaxf(d3, -MR), MR);
    double shx = (double)(x * cSTRIDE[lev]);
    double shy = (double)(y * cSTRIDE[lev]);
    float p0 = (float)(ba[lev][a][0] + shx);
    float p1 = (float)(ba[lev][a][1] + shy);
    float p2 = (float)(ba[lev][a][2] + shx);
    float p3 = (float)(ba[lev][a][3] + shy);
    float pxc = (p0 + p2) * 0.5f, pyc = (p1 + p3) * 0.5f;
    float pw = p2 - p0, ph = p3 - p1;
    float gx = pxc + pw * d0, gy = pyc + ph * d1;
    float gw = pw * expf(d2), gh = ph * expf(d3);
    float x1 = gx - 0.5f * gw, y1 = gy - 0.5f * gh;
    float x2 = gx + 0.5f * gw, y2 = gy + 0.5f * gh;
    x1 = fminf(fmaxf(x1, 0.f), 320.f);
    y1 = fminf(fmaxf(y1, 0.f), 320.f);
    x2 = fminf(fmaxf(x2, 0.f), 320.f);
    y2 = fminf(fmaxf(y2, 0.f), 320.f);
    size_t o = (size_t)b * KTOT + (size_t)r;
    boxes[o * 4 + 0] = x1; boxes[o * 4 + 1] = y1;
    boxes[o * 4 + 2] = x2; boxes[o * 4 + 3] = y2;
    oscore[o] = score;
    lab8[o] = valid ? (unsigned char)label : (unsigned char)0xFF;
    outp[(size_t)NB * KTOT * 5 + o] = (float)label;
    if (!valid) {
      float* det = outp + o * 5;
      det[0] = 0.f; det[1] = 0.f; det[2] = 0.f; det[3] = 0.f; det[4] = 0.f;
      outp[(size_t)NB * KTOT * 6 + o] = 0.f;
    }
    lmax = fmaxf(fmaxf(x1, y1), fmaxf(x2, y2));
  }
  #pragma unroll
  for (int m = 32; m; m >>= 1) lmax = fmaxf(lmax, __shfl_xor(lmax, m));
  if ((tid & 63) == 0) atomicMax(&obmax_u[b], __float_as_uint(lmax));
}

// ---------------- K4: mask-matrix NMS, one block per (image,class) ---------------
__global__ __launch_bounds__(256) void k_nms(
    const float* __restrict__ boxes, const float* __restrict__ oscore,
    const unsigned char* __restrict__ lab8, const unsigned* __restrict__ obmax_u,
    float* __restrict__ out)
{
  int blk = blockIdx.x;
  int b = blk / 80, cls = blk % 80;
  int tid = threadIdx.x;
  int lane = tid & 63, w = tid >> 6;

  __shared__ unsigned short list[NMSCAP];
  __shared__ float ox1[NMSCAP], oy1[NMSCAP], ox2[NMSCAP], oy2[NMSCAP];
  __shared__ float oar[NMSCAP], osc[NMSCAP];
  __shared__ float rx1[NMSCAP], ry1[NMSCAP], rx2[NMSCAP], ry2[NMSCAP];
  __shared__ unsigned long long mask[NMSCAP][8];
  __shared__ unsigned ccnt[24], cbase[24];
  __shared__ int sh_n;
  __shared__ unsigned long long alive_s[8];

  float ofs = (float)cls * (__uint_as_float(obmax_u[b]) + 1.0f);
  const unsigned* lb32 = (const unsigned*)(lab8 + (size_t)b * KTOT);

  unsigned long long balA[6][4];
  #pragma unroll
  for (int ci = 0; ci < 6; ++ci) {
    int chunk = w + ci * 4;
    unsigned v = 0xFFFFFFFFu;
    if (chunk < 22) {
      int u = chunk * 64 + lane;
      if (u < KTOT / 4) v = lb32[u];
    }
    unsigned long long m0 = __ballot(((v      ) & 0xFFu) == (unsigned)cls);
    unsigned long long m1 = __ballot(((v >>  8) & 0xFFu) == (unsigned)cls);
    unsigned long long m2 = __ballot(((v >> 16) & 0xFFu) == (unsigned)cls);
    unsigned long long m3 = __ballot(((v >> 24) & 0xFFu) == (unsigned)cls);
    balA[ci][0] = m0; balA[ci][1] = m1; balA[ci][2] = m2; balA[ci][3] = m3;
    if (chunk < 22 && lane == 0)
      ccnt[chunk] = (unsigned)(__popcll(m0) + __popcll(m1) + __popcll(m2) + __popcll(m3));
  }
  __syncthreads();
  if (tid == 0) {
    unsigned tot = 0;
    for (int c = 0; c < 22; ++c) { cbase[c] = tot; tot += ccnt[c]; }
    sh_n = (tot < NMSCAP) ? (int)tot : NMSCAP;
  }
  __syncthreads();
  int n = sh_n;
  unsigned long long blt = (lane == 0) ? 0ull : ((~0ull) >> (64 - lane));
  #pragma unroll
  for (int ci = 0; ci < 6; ++ci) {
    int chunk = w + ci * 4;
    if (chunk < 22) {
      unsigned pos = cbase[chunk];
      unsigned below = (unsigned)(__popcll(balA[ci][0] & blt) + __popcll(balA[ci][1] & blt) +
                                  __popcll(balA[ci][2] & blt) + __popcll(balA[ci][3] & blt));
      unsigned within = 0;
      #pragma unroll
      for (int k = 0; k < 4; ++k) {
        if ((balA[ci][k] >> lane) & 1ull) {
          unsigned mypos = pos + below + within;
          if (mypos < NMSCAP) list[mypos] = (unsigned short)(chunk * 256 + lane * 4 + k);
          ++within;
        }
      }
    }
  }
  __syncthreads();

  for (int t = tid; t < n; t += 256) {
    int pos = list[t];
    size_t o = (size_t)b * KTOT + pos;
    float4 bb = *(const float4*)(boxes + o * 4);
    rx1[t] = bb.x; ry1[t] = bb.y; rx2[t] = bb.z; ry2[t] = bb.w;
    float a1 = bb.x + ofs, b1 = bb.y + ofs, a2 = bb.z + ofs, b2 = bb.w + ofs;
    ox1[t] = a1; oy1[t] = b1; ox2[t] = a2; oy2[t] = b2;
    oar[t] = (a2 - a1) * (b2 - b1);
    osc[t] = oscore[o];
  }
  __syncthreads();

  int nw = (n + 63) >> 6;
  for (int i = tid; i < n; i += 256) {
    float ax1 = ox1[i], ay1 = oy1[i], ax2 = ox2[i], ay2 = oy2[i], aar = oar[i];
    int w0 = i >> 6;
    for (int wd = w0; wd < nw; ++wd) {
      unsigned long long m = 0;
      int jbase = wd << 6;
      int jend = n - jbase; if (jend > 64) jend = 64;
      for (int jj = 0; jj < jend; ++jj) {
        int j = jbase + jj;
        if (j > i) {
          float ix1 = fmaxf(ax1, ox1[j]);
          float iy1 = fmaxf(ay1, oy1[j]);
          float ix2 = fminf(ax2, ox2[j]);
          float iy2 = fminf(ay2, oy2[j]);
          float iw = fmaxf(ix2 - ix1, 0.f);
          float ih = fmaxf(iy2 - iy1, 0.f);
          float inter = iw * ih;
          float iou = inter / (aar + oar[j] - inter);
          if (iou > IOU_THR) m |= (1ull << jj);
        }
      }
      mask[i][wd] = m;
    }
  }
  __syncthreads();

  if (w == 0) {
    unsigned long long aw = 0;
    if (lane < nw) {
      int rem = n - (lane << 6);
      aw = (rem >= 64) ? ~0ull : ((1ull << rem) - 1ull);
    }
    for (int i = 0; i < n; ++i) {
      int wi = i >> 6;
      unsigned long long mrow = (lane >= wi && lane < nw) ? mask[i][lane] : 0ull;
      unsigned long long tw = shfl64(aw, wi);
      if ((tw >> (i & 63)) & 1ull) aw &= ~mrow;
    }
    if (lane < 8) alive_s[lane] = aw;
  }
  __syncthreads();

  for (int t = tid; t < n; t += 256) {
    float kf = ((alive_s[t >> 6] >> (t & 63)) & 1ull) ? 1.f : 0.f;
    int pos = list[t];
    size_t o = (size_t)b * KTOT + pos;
    float* det = out + o * 5;
    det[0] = rx1[t] * kf; det[1] = ry1[t] * kf;
    det[2] = rx2[t] * kf; det[3] = ry2[t] * kf;
    det[4] = osc[t] * kf;
    out[(size_t)NB * KTOT * 6 + o] = kf;
  }
}

extern "C" void kernel_launch(void* const* d_in, const int* in_sizes, int n_in,
                              void* d_out, int out_size, void* d_ws, size_t ws_size,
                              hipStream_t stream) {
  (void)in_sizes; (void)n_in; (void)out_size; (void)ws_size;
  const float* cls[6]; const float* bbx[6];
  for (int i = 0; i < 6; ++i) {
    cls[i] = (const float*)d_in[2 * i];
    bbx[i] = (const float*)d_in[2 * i + 1];
  }
  char* ws = (char*)d_ws;
  float* scores = (float*)ws;                                         // 4,139,520
  unsigned* rank_part = (unsigned*)ws;                                // aliases scores (dead after select)
  unsigned long long* selkeys = (unsigned long long*)(ws + 4139520);  // 175,360
  float* boxes  = (float*)(ws + 4314880);                             // 350,720
  float* oscore = (float*)(ws + 4665600);                             // 87,680
  unsigned char* lab8 = (unsigned char*)(ws + 4753280);               // 21,920
  unsigned* obmax_u = (unsigned*)(ws + 5016320);                      // 16 B

  k_softmax<<<NB * 78, 256, 0, stream>>>(cls[0], cls[1], cls[2], cls[3], cls[4], cls[5],
                                         scores, obmax_u);
  k_select<<<NB * 6, 1024, 0, stream>>>(scores, selkeys);
  k_rank<<<NB * ICH * JCH, 512, 0, stream>>>(selkeys, rank_part);
  k_decode<<<NB * ICH, 512, 0, stream>>>(selkeys, rank_part, bbx[0], bbx[1], bbx[2],
                                         bbx[3], bbx[4], bbx[5], boxes, oscore, lab8,
                                         obmax_u, (float*)d_out);
  k_nms<<<NB * 80, 256, 0, stream>>>(boxes, oscore, lab8, obmax_u, (float*)d_out);
}

// Round 11
// 105.374 us; speedup vs baseline: 2.9202x; 1.1108x over previous
//
#include <hip/hip_runtime.h>
#include <stdint.h>

#define NB 4
#define KTOT 5480
#define PER_IMG 258720
#define SCORE_THR 0.02f
#define IOU_THR 0.45f
#define REL_BASE 0x3CA3D70Bu   // smallest float bits > 0.02f
#define JCH 10                 // rank j-chunks
#define JSZ 548                // KTOT / JCH
#define ICH 11                 // rank/decode i-chunks (512 keys each)
#define NMSCAP 512
#define HBINS 512              // coarse hist bins: (kb-REL_BASE)>>17 in [0,366]

__constant__ int cFEAT[6]    = {20,10,5,3,2,1};
__constant__ int cSTRIDE[6]  = {16,32,64,107,160,320};
__constant__ int cMIN[6]     = {48,100,150,202,253,304};
__constant__ int cMAX[6]     = {100,150,202,253,304,320};
__constant__ int cNFLAT[6]   = {192000,48000,12000,4320,1920,480};
__constant__ int cFLATOFF[6] = {0,192000,240000,252000,256320,258240};
__constant__ int cKSEL[6]    = {1000,1000,1000,1000,1000,480};
__constant__ int cKOFF[6]    = {0,1000,2000,3000,4000,5000};
__constant__ double cRATIO[6] = {1.0,1.0,0.5,2.0,1.0/3.0,3.0};
__constant__ int eTLEV[14]   = {0,0,0,0,0,0,0,0,1,1,2,3,4,5};
__constant__ int eTCHK[14]   = {0,1,2,3,4,5,6,7,0,1,0,0,0,0};
__constant__ int eNCH[6]     = {8,2,1,1,1,1};
__constant__ int hL0[6]      = {0,42,54,60,66,72};   // softmax-block range per level
__constant__ int hLN[6]      = {42,12,6,6,6,6};

__device__ __forceinline__ unsigned long long mk_key(unsigned kb, int lev, unsigned idx) {
  return ((unsigned long long)kb << 21) |
         (unsigned long long)(0x1FFFFFu ^ (((unsigned)lev << 18) | idx));
}

__device__ __forceinline__ unsigned long long shfl64(unsigned long long x, int src) {
  int lo = __shfl((int)(unsigned)(x & 0xffffffffull), src);
  int hi = __shfl((int)(unsigned)(x >> 32), src);
  return ((unsigned long long)(unsigned)hi << 32) | (unsigned)lo;
}

// ---------------- K1: tiled softmax + per-block overwrite histogram --------------
// Block t writes bhist[t*512..] fully (no atomics -> no pre-zero needed).
// Block 0 also zeroes obmax[0..3] and ctrl[0..191] (consumed >=1 boundary later).
__global__ __launch_bounds__(256) void k_softmax(
    const float* __restrict__ c0, const float* __restrict__ c1,
    const float* __restrict__ c2, const float* __restrict__ c3,
    const float* __restrict__ c4, const float* __restrict__ c5,
    float* __restrict__ scores, unsigned* __restrict__ bhist,
    unsigned* __restrict__ obmax_u, unsigned* __restrict__ ctrl)
{
  int t = blockIdx.x;
  int tid = threadIdx.x;
  if (t == 0) {
    if (tid < 4) obmax_u[tid] = 0u;
    if (tid >= 64 && tid < 256) ctrl[tid - 64] = 0u;
  }
  int b = t / 78, rem = t % 78;
  int lev, a, cb;
  if (rem < 42)      { lev = 0; a = rem / 7;         cb = (rem % 7) * 64; }
  else if (rem < 54) { lev = 1; a = (rem - 42) >> 1; cb = ((rem - 42) & 1) * 64; }
  else               { lev = 2 + (rem - 54) / 6; a = (rem - 54) % 6; cb = 0; }
  const float* cls = (lev==0)?c0:(lev==1)?c1:(lev==2)?c2:(lev==3)?c3:(lev==4)?c4:c5;
  int f = cFEAT[lev], ff = f * f;
  int ncell = ff - cb; if (ncell > 64) ncell = 64;

  __shared__ float tile[81 * 64];
  __shared__ unsigned hcnt[HBINS];
  for (int i = tid; i < HBINS; i += 256) hcnt[i] = 0;
  const float* base = cls + (size_t)(b * 486 + a * 81) * ff + cb;
  for (int t2 = tid; t2 < 81 * 64; t2 += 256) {
    int c = t2 >> 6, cell = t2 & 63;
    if (cell < ncell)
      tile[(c << 6) | (cell ^ (c & 63))] = base[c * ff + cell];
  }
  __syncthreads();

  int lane = tid & 63, w = tid >> 6;
  for (int cell = w; cell < ncell; cell += 4) {
    float v1 = tile[(lane << 6) | (cell ^ lane)];
    float v2 = (lane <= 16) ? tile[((lane + 64) << 6) | (cell ^ lane)]
                            : __uint_as_float(0xff800000u);
    float mx = fmaxf(v1, v2);
    #pragma unroll
    for (int m = 32; m; m >>= 1) mx = fmaxf(mx, __shfl_xor(mx, m));
    float e1 = expf(v1 - mx);
    float e2 = (lane <= 16) ? expf(v2 - mx) : 0.f;
    float sm = e1 + e2;
    #pragma unroll
    for (int m = 32; m; m >>= 1) sm += __shfl_xor(sm, m);
    int row = (cb + cell) * 6 + a;
    float* out = scores + (size_t)b * PER_IMG + cFLATOFF[lev] + row * 80;
    float p1 = e1 / sm;
    out[lane] = (p1 > SCORE_THR) ? p1 : -1.f;
    if (p1 > SCORE_THR)
      atomicAdd(&hcnt[(__float_as_uint(p1) - REL_BASE) >> 17], 1u);
    if (lane < 16) {
      float p2 = e2 / sm;
      out[lane + 64] = (p2 > SCORE_THR) ? p2 : -1.f;
      if (p2 > SCORE_THR)
        atomicAdd(&hcnt[(__float_as_uint(p2) - REL_BASE) >> 17], 1u);
    }
  }
  __syncthreads();
  unsigned* hb = bhist + (size_t)t * HBINS;
  for (int i = tid; i < HBINS; i += 256) hb[i] = hcnt[i];
}

// ---------------- K2: chunked emit with inline plan from partial hists -----------
__global__ __launch_bounds__(256) void k_emit(
    const float* __restrict__ scores, const unsigned* __restrict__ bhist,
    unsigned* __restrict__ ctrl, unsigned long long* __restrict__ selkeys,
    unsigned long long* __restrict__ eqg)
{
  int b = blockIdx.x / 14, ent = blockIdx.x % 14;
  int lev = eTLEV[ent], chk = eTCHK[ent];
  int task = b * 6 + lev;
  int n = cNFLAT[lev];
  int tid = threadIdx.x;
  const float* s = scores + (size_t)b * PER_IMG + cFLATOFF[lev];
  unsigned long long* out = selkeys + (size_t)b * KTOT + cKOFF[lev];

  if (lev == 5) {  // keep all
    for (int i = tid; i < n; i += 256) {
      float v = s[i];
      unsigned kb = (v > SCORE_THR) ? __float_as_uint(v) : 0u;
      out[i] = mk_key(kb, lev, (unsigned)i);
    }
    return;
  }

  unsigned k = (unsigned)cKSEL[lev];
  __shared__ unsigned long long wbuf[1024];
  __shared__ unsigned long long ebuf[4096];
  __shared__ unsigned sc[256];
  __shared__ unsigned wcnt, ecnt, sbw, sbe, sh_mode, sh_b1;

  // ---- inline plan: sum partial hists, suffix-scan 512 bins ----
  {
    unsigned h0 = 0, h1 = 0;
    int hbase = b * 78 + hL0[lev];
    for (int j = 0; j < hLN[lev]; ++j) {
      const unsigned* hb = bhist + (size_t)(hbase + j) * HBINS;
      h0 += hb[2 * tid];
      h1 += hb[2 * tid + 1];
    }
    sc[tid] = h0 + h1;
    __syncthreads();
    for (int off = 1; off < 256; off <<= 1) {
      unsigned cur = sc[tid];
      unsigned add = (tid + off < 256) ? sc[tid + off] : 0u;
      __syncthreads();
      sc[tid] = cur + add;
      __syncthreads();
    }
    unsigned c = sc[0];
    if (tid == 0 && c < k) sh_mode = 1u;
    if (c >= k) {
      unsigned above = (tid == 255) ? 0u : sc[tid + 1];
      unsigned run = above;                 // bins > 2*tid+1
      if (run < k && run + h1 >= k) { sh_mode = 0u; sh_b1 = (unsigned)(2 * tid + 1); }
      run += h1;
      if (run < k && run + h0 >= k) { sh_mode = 0u; sh_b1 = (unsigned)(2 * tid); }
    }
    if (tid == 0) { wcnt = 0; ecnt = 0; }
    __syncthreads();
  }
  unsigned mode = sh_mode;

  int csz = n / eNCH[lev];
  int start = chk * csz;
  const float4* s4 = (const float4*)(s + start);
  int n4 = csz >> 2;

  if (mode == 0u) {
    unsigned b1 = sh_b1;
    unsigned base_lo = REL_BASE + (b1 << 17);
    unsigned base_hi = base_lo + (1u << 17);
    #pragma unroll 4
    for (int i0 = tid; i0 < n4; i0 += 256) {
      float4 vv = s4[i0];
      #pragma unroll
      for (int e2 = 0; e2 < 4; ++e2) {
        float v = (e2==0)?vv.x:(e2==1)?vv.y:(e2==2)?vv.z:vv.w;
        if (v > SCORE_THR) {
          unsigned kb = __float_as_uint(v);
          unsigned idx = (unsigned)(start + i0 * 4 + e2);
          if (kb >= base_hi) {
            unsigned p = atomicAdd(&wcnt, 1u);
            if (p < 1024u) wbuf[p] = mk_key(kb, lev, idx);
          } else if (kb >= base_lo) {
            unsigned p = atomicAdd(&ecnt, 1u);
            if (p < 4096u) ebuf[p] = mk_key(kb, lev, idx);
          }
        }
      }
    }
  } else {  // mode 1: all candidates are winners (c < k)
    #pragma unroll 4
    for (int i0 = tid; i0 < n4; i0 += 256) {
      float4 vv = s4[i0];
      #pragma unroll
      for (int e2 = 0; e2 < 4; ++e2) {
        float v = (e2==0)?vv.x:(e2==1)?vv.y:(e2==2)?vv.z:vv.w;
        if (v > SCORE_THR) {
          unsigned p = atomicAdd(&wcnt, 1u);
          if (p < 1024u) wbuf[p] = mk_key(__float_as_uint(v), lev,
                                          (unsigned)(start + i0 * 4 + e2));
        }
      }
    }
  }
  __syncthreads();
  if (tid == 0) {
    sbw = atomicAdd(&ctrl[task * 8 + 2], wcnt);
    sbe = atomicAdd(&ctrl[task * 8 + 3], ecnt);
  }
  __syncthreads();
  unsigned nw = (wcnt < 1024u) ? wcnt : 1024u;
  unsigned ne = (ecnt < 4096u) ? ecnt : 4096u;
  unsigned bw = sbw, be = sbe;
  for (unsigned t = tid; t < nw; t += 256) out[bw + t] = wbuf[t];
  for (unsigned t = tid; t < ne; t += 256) {
    unsigned g = be + t;
    if (g < 4096u) eqg[(size_t)task * 4096 + g] = ebuf[t];
  }
}

// ---------------- K3: finalize (ties / fillers / pathological radix) -------------
__global__ __launch_bounds__(1024) void k_finalize(
    const float* __restrict__ scores, const unsigned* __restrict__ bhist,
    const unsigned* __restrict__ ctrl, unsigned long long* __restrict__ selkeys,
    const unsigned long long* __restrict__ eqg)
{
  int task = blockIdx.x;
  int b = task / 6, lev = task % 6;
  if (lev == 5) return;
  int tid = threadIdx.x;
  unsigned k = (unsigned)cKSEL[lev];
  int n = cNFLAT[lev];
  const float* s = scores + (size_t)b * PER_IMG + cFLATOFF[lev];
  unsigned long long* out = selkeys + (size_t)b * KTOT + cKOFF[lev];
  unsigned levtag = (unsigned)lev << 18;

  __shared__ unsigned long long eqb[4096];
  __shared__ unsigned sc[1024];
  __shared__ unsigned sh_cnt, sh_eq, sh_byte, sh_r;

  // ---- recompute mode from partial hists ----
  unsigned hval = 0;
  if (tid < HBINS) {
    int hbase = b * 78 + hL0[lev];
    for (int j = 0; j < hLN[lev]; ++j)
      hval += bhist[(size_t)(hbase + j) * HBINS + tid];
  }
  sc[tid] = (tid < HBINS) ? hval : 0u;
  __syncthreads();
  for (int off = 1; off < 1024; off <<= 1) {
    unsigned cur = sc[tid];
    unsigned add = (tid + off < 1024) ? sc[tid + off] : 0u;
    __syncthreads();
    sc[tid] = cur + add;
    __syncthreads();
  }
  unsigned c = sc[0];
  __syncthreads();
  unsigned mode = (c >= k) ? 0u : 1u;
  bool done = false;

  if (mode == 0u) {
    unsigned cnt = ctrl[task * 8 + 2];
    unsigned e = ctrl[task * 8 + 3];
    unsigned need = k - cnt;
    if (e <= 4096u) {
      const unsigned long long* eq = eqg + (size_t)task * 4096;
      if (e == need) {
        for (unsigned t = tid; t < need; t += 1024) out[cnt + t] = eq[t];
      } else {
        unsigned P = 1; while (P < e) P <<= 1;
        for (unsigned t = tid; t < P; t += 1024) eqb[t] = (t < e) ? eq[t] : 0ull;
        __syncthreads();
        for (unsigned sz = 2; sz <= P; sz <<= 1)
          for (unsigned st = sz >> 1; st; st >>= 1) {
            for (unsigned w = tid; w < P / 2; w += 1024) {
              unsigned i = ((w & ~(st - 1)) << 1) | (w & (st - 1));
              unsigned l = i | st;
              bool up = ((i & sz) == 0);
              unsigned long long A = eqb[i], B = eqb[l];
              if ((A < B) == up) { eqb[i] = B; eqb[l] = A; }  // descending
            }
            __syncthreads();
          }
        for (unsigned t = tid; t < need; t += 1024) out[cnt + t] = eqb[t];
      }
      done = true;
    }
  } else {
    // mode 1: candidates already emitted; append (k-c) smallest-index fillers
    unsigned c2 = ctrl[task * 8 + 2];
    unsigned need = k - c2;
    unsigned base = 0;
    for (int start = 0; start < n && base < need; start += 1024) {
      int i = start + tid;
      unsigned pred = (i < n && !(s[i] > SCORE_THR)) ? 1u : 0u;
      sc[tid] = pred;
      __syncthreads();
      for (int off = 1; off < 1024; off <<= 1) {
        unsigned add = (tid >= off) ? sc[tid - off] : 0u;
        unsigned v = sc[tid];
        __syncthreads();
        sc[tid] = v + add;
        __syncthreads();
      }
      unsigned incl = sc[tid];
      unsigned total = sc[1023];
      unsigned excl = incl - pred;
      if (pred && (base + excl) < need)
        out[c2 + base + excl] =
            (unsigned long long)(0x1FFFFFu ^ (levtag | (unsigned)i));
      __syncthreads();
      base += total;
    }
    done = true;
  }

  if (!done) {
    // pathological eq overflow: exact byte-radix reselect (rewrites out[0..k))
    unsigned* hist = sc;
    unsigned* equ = (unsigned*)eqb;
    unsigned prefix = 0, r = k;
    for (int pass = 3; pass >= 0; --pass) {
      int shift = pass * 8;
      for (int i = tid; i < 256; i += 1024) hist[i] = 0;
      __syncthreads();
      for (int i = tid; i < n; i += 1024) {
        float v = s[i];
        unsigned kb = (v > SCORE_THR) ? __float_as_uint(v) : 0u;
        bool match = (pass == 3) || (((kb ^ prefix) >> (shift + 8)) == 0u);
        if (match) atomicAdd(&hist[(kb >> shift) & 255u], 1u);
      }
      __syncthreads();
      if (tid == 0) {
        unsigned cum = 0, byte = 0, rr = r;
        for (int bb = 255; bb >= 0; --bb) {
          unsigned hh = hist[bb];
          if (cum + hh >= r) { byte = (unsigned)bb; rr = r - cum; break; }
          cum += hh;
        }
        sh_byte = byte; sh_r = rr;
      }
      __syncthreads();
      prefix |= (sh_byte << shift);
      r = sh_r;
      __syncthreads();
    }
    unsigned Kstar = prefix;
    if (tid == 0) { sh_cnt = 0; sh_eq = 0; }
    __syncthreads();
    for (int i = tid; i < n; i += 1024) {
      float v = s[i];
      unsigned kb = (v > SCORE_THR) ? __float_as_uint(v) : 0u;
      if (kb > Kstar) {
        unsigned slot = atomicAdd(&sh_cnt, 1u);
        out[slot] = mk_key(kb, lev, (unsigned)i);
      } else if (kb == Kstar) {
        unsigned es = atomicAdd(&sh_eq, 1u);
        if (es < 4096u) equ[es] = (unsigned)i;
      }
    }
    __syncthreads();
    unsigned m = sh_cnt;
    unsigned e2 = (sh_eq < 4096u) ? sh_eq : 4096u;
    unsigned need2 = k - m;
    if (e2 > need2) {
      unsigned P = 1; while (P < e2) P <<= 1;
      for (unsigned t = tid; t < P; t += 1024) if (t >= e2) equ[t] = 0xFFFFFFFFu;
      __syncthreads();
      for (unsigned sz = 2; sz <= P; sz <<= 1)
        for (unsigned st = sz >> 1; st; st >>= 1) {
          for (unsigned w = tid; w < P / 2; w += 1024) {
            unsigned i = ((w & ~(st - 1)) << 1) | (w & (st - 1));
            unsigned l = i | st;
            bool up = ((i & sz) == 0);
            unsigned A = equ[i], B = equ[l];
            if ((A > B) == up) { equ[i] = B; equ[l] = A; }  // ascending
          }
          __syncthreads();
        }
    }
    __syncthreads();
    for (unsigned t = tid; t < need2; t += 1024)
      out[m + t] = ((unsigned long long)Kstar << 21) |
                   (unsigned long long)(0x1FFFFFu ^ (levtag | equ[t]));
  }
}

// ---------------- K4a: partitioned O(N^2) rank (fence-free) ----------------------
__global__ __launch_bounds__(512) void k_rank(
    const unsigned long long* __restrict__ selkeys, unsigned* __restrict__ rank_part)
{
  int blk = blockIdx.x;
  int jc = blk % JCH;
  int rest = blk / JCH;
  int ic = rest % ICH, b = rest / ICH;
  int tid = threadIdx.x;
  __shared__ __align__(16) unsigned long long sk[JSZ];
  const unsigned long long* keys = selkeys + (size_t)b * KTOT;
  for (int j = tid; j < JSZ; j += 512) sk[j] = keys[jc * JSZ + j];
  int i = ic * 512 + tid;
  unsigned long long mk = (i < KTOT) ? keys[i] : 0ull;
  __syncthreads();
  unsigned r = 0;
  const ulonglong2* sk2 = (const ulonglong2*)sk;
  #pragma unroll 8
  for (int j = 0; j < JSZ / 2; ++j) {
    ulonglong2 kk = sk2[j];
    r += (kk.x > mk) ? 1u : 0u;
    r += (kk.y > mk) ? 1u : 0u;
  }
  if (i < KTOT) rank_part[((size_t)jc * NB + b) * KTOT + i] = r;
}

// ---------------- K4b: sum partials + decode + scatter ---------------------------
__global__ __launch_bounds__(512) void k_decode(
    const unsigned long long* __restrict__ selkeys, const unsigned* __restrict__ rank_part,
    const float* __restrict__ g0, const float* __restrict__ g1,
    const float* __restrict__ g2, const float* __restrict__ g3,
    const float* __restrict__ g4, const float* __restrict__ g5,
    float* __restrict__ boxes, float* __restrict__ oscore,
    unsigned char* __restrict__ lab8, unsigned* __restrict__ obmax_u,
    float* __restrict__ outp)
{
  int b = blockIdx.x / ICH, ic = blockIdx.x % ICH;
  int tid = threadIdx.x;
  int i = ic * 512 + tid;
  __shared__ double ba[6][6][4];
  if (tid < 36) {
    int lev = tid / 6, a = tid % 6;
    double base = (double)cMIN[lev];
    double scl = (a == 1) ? sqrt((double)cMAX[lev] / (double)cMIN[lev]) : 1.0;
    double hr = sqrt(cRATIO[a]);
    double wr = 1.0 / hr;
    double wsz = base * scl * wr;
    double hsz = base * scl * hr;
    double cc = (double)cSTRIDE[lev] / 2.0;
    ba[lev][a][0] = cc - 0.5 * wsz;
    ba[lev][a][1] = cc - 0.5 * hsz;
    ba[lev][a][2] = cc + 0.5 * wsz;
    ba[lev][a][3] = cc + 0.5 * hsz;
  }
  __syncthreads();

  float lmax = 0.f;
  if (i < KTOT) {
    unsigned long long mk = selkeys[(size_t)b * KTOT + i];
    unsigned r = 0;
    #pragma unroll
    for (int jc = 0; jc < JCH; ++jc)
      r += rank_part[((size_t)jc * NB + b) * KTOT + i];
    unsigned tag = 0x1FFFFFu ^ (unsigned)(mk & 0x1FFFFFull);
    int lev = tag >> 18;
    int fi = tag & 0x3FFFF;
    unsigned vb2 = (unsigned)(mk >> 21);
    int valid = (vb2 != 0u);
    float score = valid ? __uint_as_float(vb2) : 0.f;
    int label = fi % 80;
    int arow = fi / 80;
    int a = arow % 6, cell = arow / 6;
    int f = cFEAT[lev], ff = f * f;
    int x = cell % f, y = cell / f;
    const float* gb = (lev==0)?g0:(lev==1)?g1:(lev==2)?g2:(lev==3)?g3:(lev==4)?g4:g5;
    const float* pb = gb + (size_t)(b * 24 + a * 4) * ff + y * f + x;
    float d0 = pb[0] * 0.1f, d1 = pb[ff] * 0.1f;
    float d2 = pb[2 * ff] * 0.2f, d3 = pb[3 * ff] * 0.2f;
    const float MR = (float)4.135166556742356;
    d2 = fminf(fmaxf(d2, -MR), MR);
    d3 = fminf(fmaxf(d3, -MR), MR);
    double shx = (double)(x * cSTRIDE[lev]);
    double shy = (double)(y * cSTRIDE[lev]);
    float p0 = (float)(ba[lev][a][0] + shx);
    float p1 = (float)(ba[lev][a][1] + shy);
    float p2 = (float)(ba[lev][a][2] + shx);
    float p3 = (float)(ba[lev][a][3] + shy);
    float pxc = (p0 + p2) * 0.5f, pyc = (p1 + p3) * 0.5f;
    float pw = p2 - p0, ph = p3 - p1;
    float gx = pxc + pw * d0, gy = pyc + ph * d1;
    float gw = pw * expf(d2), gh = ph * expf(d3);
    float x1 = gx - 0.5f * gw, y1 = gy - 0.5f * gh;
    float x2 = gx + 0.5f * gw, y2 = gy + 0.5f * gh;
    x1 = fminf(fmaxf(x1, 0.f), 320.f);
    y1 = fminf(fmaxf(y1, 0.f), 320.f);
    x2 = fminf(fmaxf(x2, 0.f), 320.f);
    y2 = fminf(fmaxf(y2, 0.f), 320.f);
    size_t o = (size_t)b * KTOT + (size_t)r;
    boxes[o * 4 + 0] = x1; boxes[o * 4 + 1] = y1;
    boxes[o * 4 + 2] = x2; boxes[o * 4 + 3] = y2;
    oscore[o] = score;
    lab8[o] = valid ? (unsigned char)label : (unsigned char)0xFF;
    outp[(size_t)NB * KTOT * 5 + o] = (float)label;
    if (!valid) {
      float* det = outp + o * 5;
      det[0] = 0.f; det[1] = 0.f; det[2] = 0.f; det[3] = 0.f; det[4] = 0.f;
      outp[(size_t)NB * KTOT * 6 + o] = 0.f;
    }
    lmax = fmaxf(fmaxf(x1, y1), fmaxf(x2, y2));
  }
  #pragma unroll
  for (int m = 32; m; m >>= 1) lmax = fmaxf(lmax, __shfl_xor(lmax, m));
  if ((tid & 63) == 0) atomicMax(&obmax_u[b], __float_as_uint(lmax));
}

// ---------------- K5: mask-matrix NMS, one block per (image,class) ---------------
__global__ __launch_bounds__(256) void k_nms(
    const float* __restrict__ boxes, const float* __restrict__ oscore,
    const unsigned char* __restrict__ lab8, const unsigned* __restrict__ obmax_u,
    float* __restrict__ out)
{
  int blk = blockIdx.x;
  int b = blk / 80, cls = blk % 80;
  int tid = threadIdx.x;
  int lane = tid & 63, w = tid >> 6;

  __shared__ unsigned short list[NMSCAP];
  __shared__ float ox1[NMSCAP], oy1[NMSCAP], ox2[NMSCAP], oy2[NMSCAP];
  __shared__ float oar[NMSCAP], osc[NMSCAP];
  __shared__ float rx1[NMSCAP], ry1[NMSCAP], rx2[NMSCAP], ry2[NMSCAP];
  __shared__ unsigned long long mask[NMSCAP][8];
  __shared__ unsigned ccnt[24], cbase[24];
  __shared__ int sh_n;
  __shared__ unsigned long long alive_s[8];

  float ofs = (float)cls * (__uint_as_float(obmax_u[b]) + 1.0f);
  const unsigned* lb32 = (const unsigned*)(lab8 + (size_t)b * KTOT);

  unsigned long long balA[6][4];
  #pragma unroll
  for (int ci = 0; ci < 6; ++ci) {
    int chunk = w + ci * 4;
    unsigned v = 0xFFFFFFFFu;
    if (chunk < 22) {
      int u = chunk * 64 + lane;
      if (u < KTOT / 4) v = lb32[u];
    }
    unsigned long long m0 = __ballot(((v      ) & 0xFFu) == (unsigned)cls);
    unsigned long long m1 = __ballot(((v >>  8) & 0xFFu) == (unsigned)cls);
    unsigned long long m2 = __ballot(((v >> 16) & 0xFFu) == (unsigned)cls);
    unsigned long long m3 = __ballot(((v >> 24) & 0xFFu) == (unsigned)cls);
    balA[ci][0] = m0; balA[ci][1] = m1; balA[ci][2] = m2; balA[ci][3] = m3;
    if (chunk < 22 && lane == 0)
      ccnt[chunk] = (unsigned)(__popcll(m0) + __popcll(m1) + __popcll(m2) + __popcll(m3));
  }
  __syncthreads();
  if (tid == 0) {
    unsigned tot = 0;
    for (int c = 0; c < 22; ++c) { cbase[c] = tot; tot += ccnt[c]; }
    sh_n = (tot < NMSCAP) ? (int)tot : NMSCAP;
  }
  __syncthreads();
  int n = sh_n;
  unsigned long long blt = (lane == 0) ? 0ull : ((~0ull) >> (64 - lane));
  #pragma unroll
  for (int ci = 0; ci < 6; ++ci) {
    int chunk = w + ci * 4;
    if (chunk < 22) {
      unsigned pos = cbase[chunk];
      unsigned below = (unsigned)(__popcll(balA[ci][0] & blt) + __popcll(balA[ci][1] & blt) +
                                  __popcll(balA[ci][2] & blt) + __popcll(balA[ci][3] & blt));
      unsigned within = 0;
      #pragma unroll
      for (int k = 0; k < 4; ++k) {
        if ((balA[ci][k] >> lane) & 1ull) {
          unsigned mypos = pos + below + within;
          if (mypos < NMSCAP) list[mypos] = (unsigned short)(chunk * 256 + lane * 4 + k);
          ++within;
        }
      }
    }
  }
  __syncthreads();

  for (int t = tid; t < n; t += 256) {
    int pos = list[t];
    size_t o = (size_t)b * KTOT + pos;
    float4 bb = *(const float4*)(boxes + o * 4);
    rx1[t] = bb.x; ry1[t] = bb.y; rx2[t] = bb.z; ry2[t] = bb.w;
    float a1 = bb.x + ofs, b1 = bb.y + ofs, a2 = bb.z + ofs, b2 = bb.w + ofs;
    ox1[t] = a1; oy1[t] = b1; ox2[t] = a2; oy2[t] = b2;
    oar[t] = (a2 - a1) * (b2 - b1);
    osc[t] = oscore[o];
  }
  __syncthreads();

  int nw = (n + 63) >> 6;
  for (int i = tid; i < n; i += 256) {
    float ax1 = ox1[i], ay1 = oy1[i], ax2 = ox2[i], ay2 = oy2[i], aar = oar[i];
    int w0 = i >> 6;
    for (int wd = w0; wd < nw; ++wd) {
      unsigned long long m = 0;
      int jbase = wd << 6;
      int jend = n - jbase; if (jend > 64) jend = 64;
      for (int jj = 0; jj < jend; ++jj) {
        int j = jbase + jj;
        if (j > i) {
          float ix1 = fmaxf(ax1, ox1[j]);
          float iy1 = fmaxf(ay1, oy1[j]);
          float ix2 = fminf(ax2, ox2[j]);
          float iy2 = fminf(ay2, oy2[j]);
          float iw = fmaxf(ix2 - ix1, 0.f);
          float ih = fmaxf(iy2 - iy1, 0.f);
          float inter = iw * ih;
          float iou = inter / (aar + oar[j] - inter);
          if (iou > IOU_THR) m |= (1ull << jj);
        }
      }
      mask[i][wd] = m;
    }
  }
  __syncthreads();

  if (w == 0) {
    unsigned long long aw = 0;
    if (lane < nw) {
      int rem = n - (lane << 6);
      aw = (rem >= 64) ? ~0ull : ((1ull << rem) - 1ull);
    }
    for (int i = 0; i < n; ++i) {
      int wi = i >> 6;
      unsigned long long mrow = (lane >= wi && lane < nw) ? mask[i][lane] : 0ull;
      unsigned long long tw = shfl64(aw, wi);
      if ((tw >> (i & 63)) & 1ull) aw &= ~mrow;
    }
    if (lane < 8) alive_s[lane] = aw;
  }
  __syncthreads();

  for (int t = tid; t < n; t += 256) {
    float kf = ((alive_s[t >> 6] >> (t & 63)) & 1ull) ? 1.f : 0.f;
    int pos = list[t];
    size_t o = (size_t)b * KTOT + pos;
    float* det = out + o * 5;
    det[0] = rx1[t] * kf; det[1] = ry1[t] * kf;
    det[2] = rx2[t] * kf; det[3] = ry2[t] * kf;
    det[4] = osc[t] * kf;
    out[(size_t)NB * KTOT * 6 + o] = kf;
  }
}

extern "C" void kernel_launch(void* const* d_in, const int* in_sizes, int n_in,
                              void* d_out, int out_size, void* d_ws, size_t ws_size,
                              hipStream_t stream) {
  (void)in_sizes; (void)n_in; (void)out_size; (void)ws_size;
  const float* cls[6]; const float* bbx[6];
  for (int i = 0; i < 6; ++i) {
    cls[i] = (const float*)d_in[2 * i];
    bbx[i] = (const float*)d_in[2 * i + 1];
  }
  char* ws = (char*)d_ws;
  float* scores = (float*)ws;                                         // 4,139,520
  unsigned* rank_part = (unsigned*)ws;                                // aliases scores (dead after finalize)
  unsigned long long* selkeys = (unsigned long long*)(ws + 4139520);  // 175,360
  float* boxes  = (float*)(ws + 4314880);                             // 350,720
  float* oscore = (float*)(ws + 4665600);                             // 87,680
  unsigned char* lab8 = (unsigned char*)(ws + 4753280);               // 21,920
  unsigned* obmax_u = (unsigned*)(ws + 5016320);                      // 16 B
  unsigned* ctrl    = (unsigned*)(ws + 5016576);                      // 768 B
  unsigned* bhist   = (unsigned*)(ws + 5017600);                      // 312*512*4 = 638,976
  unsigned long long* eqg = (unsigned long long*)(ws + 5656576);      // 24*4096*8 = 786,432

  k_softmax<<<NB * 78, 256, 0, stream>>>(cls[0], cls[1], cls[2], cls[3], cls[4], cls[5],
                                         scores, bhist, obmax_u, ctrl);
  k_emit<<<NB * 14, 256, 0, stream>>>(scores, bhist, ctrl, selkeys, eqg);
  k_finalize<<<24, 1024, 0, stream>>>(scores, bhist, ctrl, selkeys, eqg);
  k_rank<<<NB * ICH * JCH, 512, 0, stream>>>(selkeys, rank_part);
  k_decode<<<NB * ICH, 512, 0, stream>>>(selkeys, rank_part, bbx[0], bbx[1], bbx[2],
                                         bbx[3], bbx[4], bbx[5], boxes, oscore, lab8,
                                         obmax_u, (float*)d_out);
  k_nms<<<NB * 80, 256, 0, stream>>>(boxes, oscore, lab8, obmax_u, (float*)d_out);
}

// Round 12
// 96.064 us; speedup vs baseline: 3.2032x; 1.0969x over previous
//
#include <hip/hip_runtime.h>
#include <stdint.h>

#define NB 4
#define KTOT 5480
#define PER_IMG 258720
#define SCORE_THR 0.02f
#define IOU_THR 0.45f
#define REL_BASE 0x3CA3D70Bu   // smallest float bits > 0.02f
#define JCH 10                 // rank j-chunks
#define JSZ 548                // KTOT / JCH
#define ICH 11                 // rank/decode i-chunks (512 keys each)
#define NMSCAP 512
#define HBINS 256              // coarse hist bins: (kb-REL_BASE)>>18 in [0,182]
#define HPART 42               // max partials per task (lev0)

__constant__ int cFEAT[6]    = {20,10,5,3,2,1};
__constant__ int cSTRIDE[6]  = {16,32,64,107,160,320};
__constant__ int cMIN[6]     = {48,100,150,202,253,304};
__constant__ int cMAX[6]     = {100,150,202,253,304,320};
__constant__ int cNFLAT[6]   = {192000,48000,12000,4320,1920,480};
__constant__ int cFLATOFF[6] = {0,192000,240000,252000,256320,258240};
__constant__ int cKSEL[6]    = {1000,1000,1000,1000,1000,480};
__constant__ int cKOFF[6]    = {0,1000,2000,3000,4000,5000};
__constant__ double cRATIO[6] = {1.0,1.0,0.5,2.0,1.0/3.0,3.0};
// emit entries: 16 lev0 chunks, 4 lev1 chunks, 1 each lev2..5 -> 24 per image
__constant__ int eTLEV[24] = {0,0,0,0,0,0,0,0,0,0,0,0,0,0,0,0, 1,1,1,1, 2,3,4,5};
__constant__ int eTCHK[24] = {0,1,2,3,4,5,6,7,8,9,10,11,12,13,14,15, 0,1,2,3, 0,0,0,0};
__constant__ int eNCH[6]   = {16,4,1,1,1,1};
__constant__ int hL0[6]    = {0,42,54,60,66,72};   // softmax-block range per level
__constant__ int hLN[6]    = {42,12,6,6,6,6};

__device__ __forceinline__ unsigned long long mk_key(unsigned kb, int lev, unsigned idx) {
  return ((unsigned long long)kb << 21) |
         (unsigned long long)(0x1FFFFFu ^ (((unsigned)lev << 18) | idx));
}

__device__ __forceinline__ unsigned long long shfl64(unsigned long long x, int src) {
  int lo = __shfl((int)(unsigned)(x & 0xffffffffull), src);
  int hi = __shfl((int)(unsigned)(x >> 32), src);
  return ((unsigned long long)(unsigned)hi << 32) | (unsigned)lo;
}

// ---------------- K1: tiled softmax + per-block overwrite histogram --------------
// bhist layout is BIN-MAJOR: bhist[(task*HBINS + bin)*HPART + j]; block j of the
// task writes column j (no atomics, no pre-zero; unwritten j never read).
__global__ __launch_bounds__(256) void k_softmax(
    const float* __restrict__ c0, const float* __restrict__ c1,
    const float* __restrict__ c2, const float* __restrict__ c3,
    const float* __restrict__ c4, const float* __restrict__ c5,
    float* __restrict__ scores, unsigned* __restrict__ bhist,
    unsigned* __restrict__ obmax_u, unsigned* __restrict__ ctrl)
{
  int t = blockIdx.x;
  int tid = threadIdx.x;
  if (t == 0) {
    if (tid < 4) obmax_u[tid] = 0u;
    if (tid >= 64 && tid < 256) ctrl[tid - 64] = 0u;
  }
  int b = t / 78, rem = t % 78;
  int lev, a, cb;
  if (rem < 42)      { lev = 0; a = rem / 7;         cb = (rem % 7) * 64; }
  else if (rem < 54) { lev = 1; a = (rem - 42) >> 1; cb = ((rem - 42) & 1) * 64; }
  else               { lev = 2 + (rem - 54) / 6; a = (rem - 54) % 6; cb = 0; }
  const float* cls = (lev==0)?c0:(lev==1)?c1:(lev==2)?c2:(lev==3)?c3:(lev==4)?c4:c5;
  int f = cFEAT[lev], ff = f * f;
  int ncell = ff - cb; if (ncell > 64) ncell = 64;

  __shared__ float tile[81 * 64];
  __shared__ unsigned hcnt[HBINS];
  if (tid < HBINS) hcnt[tid] = 0;
  const float* base = cls + (size_t)(b * 486 + a * 81) * ff + cb;
  for (int t2 = tid; t2 < 81 * 64; t2 += 256) {
    int c = t2 >> 6, cell = t2 & 63;
    if (cell < ncell)
      tile[(c << 6) | (cell ^ (c & 63))] = base[c * ff + cell];
  }
  __syncthreads();

  int lane = tid & 63, w = tid >> 6;
  for (int cell = w; cell < ncell; cell += 4) {
    float v1 = tile[(lane << 6) | (cell ^ lane)];
    float v2 = (lane <= 16) ? tile[((lane + 64) << 6) | (cell ^ lane)]
                            : __uint_as_float(0xff800000u);
    float mx = fmaxf(v1, v2);
    #pragma unroll
    for (int m = 32; m; m >>= 1) mx = fmaxf(mx, __shfl_xor(mx, m));
    float e1 = expf(v1 - mx);
    float e2 = (lane <= 16) ? expf(v2 - mx) : 0.f;
    float sm = e1 + e2;
    #pragma unroll
    for (int m = 32; m; m >>= 1) sm += __shfl_xor(sm, m);
    int row = (cb + cell) * 6 + a;
    float* out = scores + (size_t)b * PER_IMG + cFLATOFF[lev] + row * 80;
    float p1 = e1 / sm;
    out[lane] = (p1 > SCORE_THR) ? p1 : -1.f;
    if (p1 > SCORE_THR)
      atomicAdd(&hcnt[(__float_as_uint(p1) - REL_BASE) >> 18], 1u);
    if (lane < 16) {
      float p2 = e2 / sm;
      out[lane + 64] = (p2 > SCORE_THR) ? p2 : -1.f;
      if (p2 > SCORE_THR)
        atomicAdd(&hcnt[(__float_as_uint(p2) - REL_BASE) >> 18], 1u);
    }
  }
  __syncthreads();
  int task = b * 6 + lev;
  int j = rem - hL0[lev];
  if (tid < HBINS)
    bhist[((size_t)task * HBINS + tid) * HPART + j] = hcnt[tid];
}

// ---------------- K2: chunked emit with inline plan (bin-major hist sum) ---------
__global__ __launch_bounds__(256) void k_emit(
    const float* __restrict__ scores, const unsigned* __restrict__ bhist,
    unsigned* __restrict__ ctrl, unsigned long long* __restrict__ selkeys,
    unsigned long long* __restrict__ eqg)
{
  int b = blockIdx.x / 24, ent = blockIdx.x % 24;
  int lev = eTLEV[ent], chk = eTCHK[ent];
  int task = b * 6 + lev;
  int n = cNFLAT[lev];
  int tid = threadIdx.x;
  const float* s = scores + (size_t)b * PER_IMG + cFLATOFF[lev];
  unsigned long long* out = selkeys + (size_t)b * KTOT + cKOFF[lev];

  if (lev == 5) {  // keep all
    for (int i = tid; i < n; i += 256) {
      float v = s[i];
      unsigned kb = (v > SCORE_THR) ? __float_as_uint(v) : 0u;
      out[i] = mk_key(kb, lev, (unsigned)i);
    }
    return;
  }

  unsigned k = (unsigned)cKSEL[lev];
  __shared__ unsigned long long wbuf[1024];
  __shared__ unsigned long long ebuf[4096];
  __shared__ unsigned sc[256];
  __shared__ unsigned wcnt, ecnt, sbw, sbe, sh_mode, sh_b1;

  // ---- inline plan: bin-major sum (contiguous), suffix-scan 256 bins ----
  {
    const unsigned* hb = bhist + ((size_t)task * HBINS + tid) * HPART;
    int np = hLN[lev];
    unsigned cnt = 0;
    for (int j = 0; j < np; ++j) cnt += hb[j];   // contiguous: ~3 cache lines
    sc[tid] = cnt;
    __syncthreads();
    for (int off = 1; off < 256; off <<= 1) {
      unsigned cur = sc[tid];
      unsigned add = (tid + off < 256) ? sc[tid + off] : 0u;
      __syncthreads();
      sc[tid] = cur + add;
      __syncthreads();
    }
    unsigned c = sc[0];
    if (tid == 0 && c < k) sh_mode = 1u;
    if (c >= k) {
      unsigned above = (tid == 255) ? 0u : sc[tid + 1];
      if (above < k && above + cnt >= k) { sh_mode = 0u; sh_b1 = (unsigned)tid; }
    }
    if (tid == 0) { wcnt = 0; ecnt = 0; }
    __syncthreads();
  }
  unsigned mode = sh_mode;

  int csz = n / eNCH[lev];
  int start = chk * csz;
  const float4* s4 = (const float4*)(s + start);
  int n4 = csz >> 2;

  if (mode == 0u) {
    unsigned b1 = sh_b1;
    unsigned base_lo = REL_BASE + (b1 << 18);
    unsigned base_hi = base_lo + (1u << 18);
    #pragma unroll 4
    for (int i0 = tid; i0 < n4; i0 += 256) {
      float4 vv = s4[i0];
      #pragma unroll
      for (int e2 = 0; e2 < 4; ++e2) {
        float v = (e2==0)?vv.x:(e2==1)?vv.y:(e2==2)?vv.z:vv.w;
        if (v > SCORE_THR) {
          unsigned kb = __float_as_uint(v);
          unsigned idx = (unsigned)(start + i0 * 4 + e2);
          if (kb >= base_hi) {
            unsigned p = atomicAdd(&wcnt, 1u);
            if (p < 1024u) wbuf[p] = mk_key(kb, lev, idx);
          } else if (kb >= base_lo) {
            unsigned p = atomicAdd(&ecnt, 1u);
            if (p < 4096u) ebuf[p] = mk_key(kb, lev, idx);
          }
        }
      }
    }
  } else {  // mode 1: all candidates are winners (c < k)
    #pragma unroll 4
    for (int i0 = tid; i0 < n4; i0 += 256) {
      float4 vv = s4[i0];
      #pragma unroll
      for (int e2 = 0; e2 < 4; ++e2) {
        float v = (e2==0)?vv.x:(e2==1)?vv.y:(e2==2)?vv.z:vv.w;
        if (v > SCORE_THR) {
          unsigned p = atomicAdd(&wcnt, 1u);
          if (p < 1024u) wbuf[p] = mk_key(__float_as_uint(v), lev,
                                          (unsigned)(start + i0 * 4 + e2));
        }
      }
    }
  }
  __syncthreads();
  if (tid == 0) {
    sbw = atomicAdd(&ctrl[task * 8 + 2], wcnt);
    sbe = atomicAdd(&ctrl[task * 8 + 3], ecnt);
  }
  __syncthreads();
  unsigned nw = (wcnt < 1024u) ? wcnt : 1024u;
  unsigned ne = (ecnt < 4096u) ? ecnt : 4096u;
  unsigned bw = sbw, be = sbe;
  for (unsigned t = tid; t < nw; t += 256) out[bw + t] = wbuf[t];
  for (unsigned t = tid; t < ne; t += 256) {
    unsigned g = be + t;
    if (g < 4096u) eqg[(size_t)task * 4096 + g] = ebuf[t];
  }
}

// ---------------- K3: finalize (ties / fillers / pathological radix) -------------
__global__ __launch_bounds__(1024) void k_finalize(
    const float* __restrict__ scores, const unsigned* __restrict__ bhist,
    const unsigned* __restrict__ ctrl, unsigned long long* __restrict__ selkeys,
    const unsigned long long* __restrict__ eqg)
{
  int task = blockIdx.x;
  int b = task / 6, lev = task % 6;
  if (lev == 5) return;
  int tid = threadIdx.x;
  unsigned k = (unsigned)cKSEL[lev];
  int n = cNFLAT[lev];
  const float* s = scores + (size_t)b * PER_IMG + cFLATOFF[lev];
  unsigned long long* out = selkeys + (size_t)b * KTOT + cKOFF[lev];
  unsigned levtag = (unsigned)lev << 18;

  __shared__ unsigned long long eqb[4096];
  __shared__ unsigned sc[1024];
  __shared__ unsigned sh_cnt, sh_eq, sh_byte, sh_r;

  // ---- recompute candidate count from bin-major partials ----
  unsigned hval = 0;
  if (tid < HBINS) {
    const unsigned* hb = bhist + ((size_t)task * HBINS + tid) * HPART;
    int np = hLN[lev];
    for (int j = 0; j < np; ++j) hval += hb[j];
  }
  sc[tid] = (tid < HBINS) ? hval : 0u;
  __syncthreads();
  for (int off = 128; off >= 1; off >>= 1) {
    if (tid < off) sc[tid] += sc[tid + off];
    __syncthreads();
  }
  unsigned c = sc[0];
  __syncthreads();
  unsigned mode = (c >= k) ? 0u : 1u;
  bool done = false;

  if (mode == 0u) {
    unsigned cnt = ctrl[task * 8 + 2];
    unsigned e = ctrl[task * 8 + 3];
    unsigned need = k - cnt;
    if (e <= 4096u) {
      const unsigned long long* eq = eqg + (size_t)task * 4096;
      if (e == need) {
        for (unsigned t = tid; t < need; t += 1024) out[cnt + t] = eq[t];
      } else {
        unsigned P = 1; while (P < e) P <<= 1;
        for (unsigned t = tid; t < P; t += 1024) eqb[t] = (t < e) ? eq[t] : 0ull;
        __syncthreads();
        for (unsigned sz = 2; sz <= P; sz <<= 1)
          for (unsigned st = sz >> 1; st; st >>= 1) {
            for (unsigned w = tid; w < P / 2; w += 1024) {
              unsigned i = ((w & ~(st - 1)) << 1) | (w & (st - 1));
              unsigned l = i | st;
              bool up = ((i & sz) == 0);
              unsigned long long A = eqb[i], B = eqb[l];
              if ((A < B) == up) { eqb[i] = B; eqb[l] = A; }  // descending
            }
            __syncthreads();
          }
        for (unsigned t = tid; t < need; t += 1024) out[cnt + t] = eqb[t];
      }
      done = true;
    }
  } else {
    // mode 1: candidates already emitted; append (k-c) smallest-index fillers
    unsigned c2 = ctrl[task * 8 + 2];
    unsigned need = k - c2;
    unsigned base = 0;
    for (int start = 0; start < n && base < need; start += 1024) {
      int i = start + tid;
      unsigned pred = (i < n && !(s[i] > SCORE_THR)) ? 1u : 0u;
      sc[tid] = pred;
      __syncthreads();
      for (int off = 1; off < 1024; off <<= 1) {
        unsigned add = (tid >= off) ? sc[tid - off] : 0u;
        unsigned v = sc[tid];
        __syncthreads();
        sc[tid] = v + add;
        __syncthreads();
      }
      unsigned incl = sc[tid];
      unsigned total = sc[1023];
      unsigned excl = incl - pred;
      if (pred && (base + excl) < need)
        out[c2 + base + excl] =
            (unsigned long long)(0x1FFFFFu ^ (levtag | (unsigned)i));
      __syncthreads();
      base += total;
    }
    done = true;
  }

  if (!done) {
    // pathological eq overflow: exact byte-radix reselect (rewrites out[0..k))
    unsigned* hist = sc;
    unsigned* equ = (unsigned*)eqb;
    unsigned prefix = 0, r = k;
    for (int pass = 3; pass >= 0; --pass) {
      int shift = pass * 8;
      for (int i = tid; i < 256; i += 1024) hist[i] = 0;
      __syncthreads();
      for (int i = tid; i < n; i += 1024) {
        float v = s[i];
        unsigned kb = (v > SCORE_THR) ? __float_as_uint(v) : 0u;
        bool match = (pass == 3) || (((kb ^ prefix) >> (shift + 8)) == 0u);
        if (match) atomicAdd(&hist[(kb >> shift) & 255u], 1u);
      }
      __syncthreads();
      if (tid == 0) {
        unsigned cum = 0, byte = 0, rr = r;
        for (int bb = 255; bb >= 0; --bb) {
          unsigned hh = hist[bb];
          if (cum + hh >= r) { byte = (unsigned)bb; rr = r - cum; break; }
          cum += hh;
        }
        sh_byte = byte; sh_r = rr;
      }
      __syncthreads();
      prefix |= (sh_byte << shift);
      r = sh_r;
      __syncthreads();
    }
    unsigned Kstar = prefix;
    if (tid == 0) { sh_cnt = 0; sh_eq = 0; }
    __syncthreads();
    for (int i = tid; i < n; i += 1024) {
      float v = s[i];
      unsigned kb = (v > SCORE_THR) ? __float_as_uint(v) : 0u;
      if (kb > Kstar) {
        unsigned slot = atomicAdd(&sh_cnt, 1u);
        out[slot] = mk_key(kb, lev, (unsigned)i);
      } else if (kb == Kstar) {
        unsigned es = atomicAdd(&sh_eq, 1u);
        if (es < 4096u) equ[es] = (unsigned)i;
      }
    }
    __syncthreads();
    unsigned m = sh_cnt;
    unsigned e2 = (sh_eq < 4096u) ? sh_eq : 4096u;
    unsigned need2 = k - m;
    if (e2 > need2) {
      unsigned P = 1; while (P < e2) P <<= 1;
      for (unsigned t = tid; t < P; t += 1024) if (t >= e2) equ[t] = 0xFFFFFFFFu;
      __syncthreads();
      for (unsigned sz = 2; sz <= P; sz <<= 1)
        for (unsigned st = sz >> 1; st; st >>= 1) {
          for (unsigned w = tid; w < P / 2; w += 1024) {
            unsigned i = ((w & ~(st - 1)) << 1) | (w & (st - 1));
            unsigned l = i | st;
            bool up = ((i & sz) == 0);
            unsigned A = equ[i], B = equ[l];
            if ((A > B) == up) { equ[i] = B; equ[l] = A; }  // ascending
          }
          __syncthreads();
        }
    }
    __syncthreads();
    for (unsigned t = tid; t < need2; t += 1024)
      out[m + t] = ((unsigned long long)Kstar << 21) |
                   (unsigned long long)(0x1FFFFFu ^ (levtag | equ[t]));
  }
}

// ---------------- K4a: partitioned O(N^2) rank (fence-free) ----------------------
__global__ __launch_bounds__(512) void k_rank(
    const unsigned long long* __restrict__ selkeys, unsigned* __restrict__ rank_part)
{
  int blk = blockIdx.x;
  int jc = blk % JCH;
  int rest = blk / JCH;
  int ic = rest % ICH, b = rest / ICH;
  int tid = threadIdx.x;
  __shared__ __align__(16) unsigned long long sk[JSZ];
  const unsigned long long* keys = selkeys + (size_t)b * KTOT;
  for (int j = tid; j < JSZ; j += 512) sk[j] = keys[jc * JSZ + j];
  int i = ic * 512 + tid;
  unsigned long long mk = (i < KTOT) ? keys[i] : 0ull;
  __syncthreads();
  unsigned r = 0;
  const ulonglong2* sk2 = (const ulonglong2*)sk;
  #pragma unroll 8
  for (int j = 0; j < JSZ / 2; ++j) {
    ulonglong2 kk = sk2[j];
    r += (kk.x > mk) ? 1u : 0u;
    r += (kk.y > mk) ? 1u : 0u;
  }
  if (i < KTOT) rank_part[((size_t)jc * NB + b) * KTOT + i] = r;
}

// ---------------- K4b: sum partials + decode + scatter ---------------------------
__global__ __launch_bounds__(512) void k_decode(
    const unsigned long long* __restrict__ selkeys, const unsigned* __restrict__ rank_part,
    const float* __restrict__ g0, const float* __restrict__ g1,
    const float* __restrict__ g2, const float* __restrict__ g3,
    const float* __restrict__ g4, const float* __restrict__ g5,
    float* __restrict__ boxes, float* __restrict__ oscore,
    unsigned char* __restrict__ lab8, unsigned* __restrict__ obmax_u,
    float* __restrict__ outp)
{
  int b = blockIdx.x / ICH, ic = blockIdx.x % ICH;
  int tid = threadIdx.x;
  int i = ic * 512 + tid;
  __shared__ double ba[6][6][4];
  if (tid < 36) {
    int lev = tid / 6, a = tid % 6;
    double base = (double)cMIN[lev];
    double scl = (a == 1) ? sqrt((double)cMAX[lev] / (double)cMIN[lev]) : 1.0;
    double hr = sqrt(cRATIO[a]);
    double wr = 1.0 / hr;
    double wsz = base * scl * wr;
    double hsz = base * scl * hr;
    double cc = (double)cSTRIDE[lev] / 2.0;
    ba[lev][a][0] = cc - 0.5 * wsz;
    ba[lev][a][1] = cc - 0.5 * hsz;
    ba[lev][a][2] = cc + 0.5 * wsz;
    ba[lev][a][3] = cc + 0.5 * hsz;
  }
  __syncthreads();

  float lmax = 0.f;
  if (i < KTOT) {
    unsigned long long mk = selkeys[(size_t)b * KTOT + i];
    unsigned r = 0;
    #pragma unroll
    for (int jc = 0; jc < JCH; ++jc)
      r += rank_part[((size_t)jc * NB + b) * KTOT + i];
    unsigned tag = 0x1FFFFFu ^ (unsigned)(mk & 0x1FFFFFull);
    int lev = tag >> 18;
    int fi = tag & 0x3FFFF;
    unsigned vb2 = (unsigned)(mk >> 21);
    int valid = (vb2 != 0u);
    float score = valid ? __uint_as_float(vb2) : 0.f;
    int label = fi % 80;
    int arow = fi / 80;
    int a = arow % 6, cell = arow / 6;
    int f = cFEAT[lev], ff = f * f;
    int x = cell % f, y = cell / f;
    const float* gb = (lev==0)?g0:(lev==1)?g1:(lev==2)?g2:(lev==3)?g3:(lev==4)?g4:g5;
    const float* pb = gb + (size_t)(b * 24 + a * 4) * ff + y * f + x;
    float d0 = pb[0] * 0.1f, d1 = pb[ff] * 0.1f;
    float d2 = pb[2 * ff] * 0.2f, d3 = pb[3 * ff] * 0.2f;
    const float MR = (float)4.135166556742356;
    d2 = fminf(fmaxf(d2, -MR), MR);
    d3 = fminf(fmaxf(d3, -MR), MR);
    double shx = (double)(x * cSTRIDE[lev]);
    double shy = (double)(y * cSTRIDE[lev]);
    float p0 = (float)(ba[lev][a][0] + shx);
    float p1 = (float)(ba[lev][a][1] + shy);
    float p2 = (float)(ba[lev][a][2] + shx);
    float p3 = (float)(ba[lev][a][3] + shy);
    float pxc = (p0 + p2) * 0.5f, pyc = (p1 + p3) * 0.5f;
    float pw = p2 - p0, ph = p3 - p1;
    float gx = pxc + pw * d0, gy = pyc + ph * d1;
    float gw = pw * expf(d2), gh = ph * expf(d3);
    float x1 = gx - 0.5f * gw, y1 = gy - 0.5f * gh;
    float x2 = gx + 0.5f * gw, y2 = gy + 0.5f * gh;
    x1 = fminf(fmaxf(x1, 0.f), 320.f);
    y1 = fminf(fmaxf(y1, 0.f), 320.f);
    x2 = fminf(fmaxf(x2, 0.f), 320.f);
    y2 = fminf(fmaxf(y2, 0.f), 320.f);
    size_t o = (size_t)b * KTOT + (size_t)r;
    boxes[o * 4 + 0] = x1; boxes[o * 4 + 1] = y1;
    boxes[o * 4 + 2] = x2; boxes[o * 4 + 3] = y2;
    oscore[o] = score;
    lab8[o] = valid ? (unsigned char)label : (unsigned char)0xFF;
    outp[(size_t)NB * KTOT * 5 + o] = (float)label;
    if (!valid) {
      float* det = outp + o * 5;
      det[0] = 0.f; det[1] = 0.f; det[2] = 0.f; det[3] = 0.f; det[4] = 0.f;
      outp[(size_t)NB * KTOT * 6 + o] = 0.f;
    }
    lmax = fmaxf(fmaxf(x1, y1), fmaxf(x2, y2));
  }
  #pragma unroll
  for (int m = 32; m; m >>= 1) lmax = fmaxf(lmax, __shfl_xor(lmax, m));
  if ((tid & 63) == 0) atomicMax(&obmax_u[b], __float_as_uint(lmax));
}

// ---------------- K5: mask-matrix NMS, one block per (image,class) ---------------
__global__ __launch_bounds__(256) void k_nms(
    const float* __restrict__ boxes, const float* __restrict__ oscore,
    const unsigned char* __restrict__ lab8, const unsigned* __restrict__ obmax_u,
    float* __restrict__ out)
{
  int blk = blockIdx.x;
  int b = blk / 80, cls = blk % 80;
  int tid = threadIdx.x;
  int lane = tid & 63, w = tid >> 6;

  __shared__ unsigned short list[NMSCAP];
  __shared__ float ox1[NMSCAP], oy1[NMSCAP], ox2[NMSCAP], oy2[NMSCAP];
  __shared__ float oar[NMSCAP], osc[NMSCAP];
  __shared__ float rx1[NMSCAP], ry1[NMSCAP], rx2[NMSCAP], ry2[NMSCAP];
  __shared__ unsigned long long mask[NMSCAP][8];
  __shared__ unsigned ccnt[24], cbase[24];
  __shared__ int sh_n;
  __shared__ unsigned long long alive_s[8];

  float ofs = (float)cls * (__uint_as_float(obmax_u[b]) + 1.0f);
  const unsigned* lb32 = (const unsigned*)(lab8 + (size_t)b * KTOT);

  unsigned long long balA[6][4];
  #pragma unroll
  for (int ci = 0; ci < 6; ++ci) {
    int chunk = w + ci * 4;
    unsigned v = 0xFFFFFFFFu;
    if (chunk < 22) {
      int u = chunk * 64 + lane;
      if (u < KTOT / 4) v = lb32[u];
    }
    unsigned long long m0 = __ballot(((v      ) & 0xFFu) == (unsigned)cls);
    unsigned long long m1 = __ballot(((v >>  8) & 0xFFu) == (unsigned)cls);
    unsigned long long m2 = __ballot(((v >> 16) & 0xFFu) == (unsigned)cls);
    unsigned long long m3 = __ballot(((v >> 24) & 0xFFu) == (unsigned)cls);
    balA[ci][0] = m0; balA[ci][1] = m1; balA[ci][2] = m2; balA[ci][3] = m3;
    if (chunk < 22 && lane == 0)
      ccnt[chunk] = (unsigned)(__popcll(m0) + __popcll(m1) + __popcll(m2) + __popcll(m3));
  }
  __syncthreads();
  if (tid == 0) {
    unsigned tot = 0;
    for (int c = 0; c < 22; ++c) { cbase[c] = tot; tot += ccnt[c]; }
    sh_n = (tot < NMSCAP) ? (int)tot : NMSCAP;
  }
  __syncthreads();
  int n = sh_n;
  unsigned long long blt = (lane == 0) ? 0ull : ((~0ull) >> (64 - lane));
  #pragma unroll
  for (int ci = 0; ci < 6; ++ci) {
    int chunk = w + ci * 4;
    if (chunk < 22) {
      unsigned pos = cbase[chunk];
      unsigned below = (unsigned)(__popcll(balA[ci][0] & blt) + __popcll(balA[ci][1] & blt) +
                                  __popcll(balA[ci][2] & blt) + __popcll(balA[ci][3] & blt));
      unsigned within = 0;
      #pragma unroll
      for (int k = 0; k < 4; ++k) {
        if ((balA[ci][k] >> lane) & 1ull) {
          unsigned mypos = pos + below + within;
          if (mypos < NMSCAP) list[mypos] = (unsigned short)(chunk * 256 + lane * 4 + k);
          ++within;
        }
      }
    }
  }
  __syncthreads();

  for (int t = tid; t < n; t += 256) {
    int pos = list[t];
    size_t o = (size_t)b * KTOT + pos;
    float4 bb = *(const float4*)(boxes + o * 4);
    rx1[t] = bb.x; ry1[t] = bb.y; rx2[t] = bb.z; ry2[t] = bb.w;
    float a1 = bb.x + ofs, b1 = bb.y + ofs, a2 = bb.z + ofs, b2 = bb.w + ofs;
    ox1[t] = a1; oy1[t] = b1; ox2[t] = a2; oy2[t] = b2;
    oar[t] = (a2 - a1) * (b2 - b1);
    osc[t] = oscore[o];
  }
  __syncthreads();

  int nw = (n + 63) >> 6;
  for (int i = tid; i < n; i += 256) {
    float ax1 = ox1[i], ay1 = oy1[i], ax2 = ox2[i], ay2 = oy2[i], aar = oar[i];
    int w0 = i >> 6;
    for (int wd = w0; wd < nw; ++wd) {
      unsigned long long m = 0;
      int jbase = wd << 6;
      int jend = n - jbase; if (jend > 64) jend = 64;
      for (int jj = 0; jj < jend; ++jj) {
        int j = jbase + jj;
        if (j > i) {
          float ix1 = fmaxf(ax1, ox1[j]);
          float iy1 = fmaxf(ay1, oy1[j]);
          float ix2 = fminf(ax2, ox2[j]);
          float iy2 = fminf(ay2, oy2[j]);
          float iw = fmaxf(ix2 - ix1, 0.f);
          float ih = fmaxf(iy2 - iy1, 0.f);
          float inter = iw * ih;
          float iou = inter / (aar + oar[j] - inter);
          if (iou > IOU_THR) m |= (1ull << jj);
        }
      }
      mask[i][wd] = m;
    }
  }
  __syncthreads();

  if (w == 0) {
    unsigned long long aw = 0;
    if (lane < nw) {
      int rem = n - (lane << 6);
      aw = (rem >= 64) ? ~0ull : ((1ull << rem) - 1ull);
    }
    for (int i = 0; i < n; ++i) {
      int wi = i >> 6;
      unsigned long long mrow = (lane >= wi && lane < nw) ? mask[i][lane] : 0ull;
      unsigned long long tw = shfl64(aw, wi);
      if ((tw >> (i & 63)) & 1ull) aw &= ~mrow;
    }
    if (lane < 8) alive_s[lane] = aw;
  }
  __syncthreads();

  for (int t = tid; t < n; t += 256) {
    float kf = ((alive_s[t >> 6] >> (t & 63)) & 1ull) ? 1.f : 0.f;
    int pos = list[t];
    size_t o = (size_t)b * KTOT + pos;
    float* det = out + o * 5;
    det[0] = rx1[t] * kf; det[1] = ry1[t] * kf;
    det[2] = rx2[t] * kf; det[3] = ry2[t] * kf;
    det[4] = osc[t] * kf;
    out[(size_t)NB * KTOT * 6 + o] = kf;
  }
}

extern "C" void kernel_launch(void* const* d_in, const int* in_sizes, int n_in,
                              void* d_out, int out_size, void* d_ws, size_t ws_size,
                              hipStream_t stream) {
  (void)in_sizes; (void)n_in; (void)out_size; (void)ws_size;
  const float* cls[6]; const float* bbx[6];
  for (int i = 0; i < 6; ++i) {
    cls[i] = (const float*)d_in[2 * i];
    bbx[i] = (const float*)d_in[2 * i + 1];
  }
  char* ws = (char*)d_ws;
  float* scores = (float*)ws;                                         // 4,139,520
  unsigned* rank_part = (unsigned*)ws;                                // aliases scores (dead after finalize)
  unsigned long long* selkeys = (unsigned long long*)(ws + 4139520);  // 175,360
  float* boxes  = (float*)(ws + 4314880);                             // 350,720
  float* oscore = (float*)(ws + 4665600);                             // 87,680
  unsigned char* lab8 = (unsigned char*)(ws + 4753280);               // 21,920
  unsigned* obmax_u = (unsigned*)(ws + 5016320);                      // 16 B
  unsigned* ctrl    = (unsigned*)(ws + 5016576);                      // 768 B
  unsigned* bhist   = (unsigned*)(ws + 5017600);                      // 24*256*42*4 = 1,032,192
  unsigned long long* eqg = (unsigned long long*)(ws + 6049792);      // 786,432 -> ends 6,836,224

  k_softmax<<<NB * 78, 256, 0, stream>>>(cls[0], cls[1], cls[2], cls[3], cls[4], cls[5],
                                         scores, bhist, obmax_u, ctrl);
  k_emit<<<NB * 24, 256, 0, stream>>>(scores, bhist, ctrl, selkeys, eqg);
  k_finalize<<<24, 1024, 0, stream>>>(scores, bhist, ctrl, selkeys, eqg);
  k_rank<<<NB * ICH * JCH, 512, 0, stream>>>(selkeys, rank_part);
  k_decode<<<NB * ICH, 512, 0, stream>>>(selkeys, rank_part, bbx[0], bbx[1], bbx[2],
                                         bbx[3], bbx[4], bbx[5], boxes, oscore, lab8,
                                         obmax_u, (float*)d_out);
  k_nms<<<NB * 80, 256, 0, stream>>>(boxes, oscore, lab8, obmax_u, (float*)d_out);
}